// Round 7
// baseline (3052.570 us; speedup 1.0000x reference)
//
#include <hip/hip_runtime.h>
#include <math.h>

typedef unsigned short u16;
typedef unsigned int u32;
typedef unsigned long long u64;

// dims
#define NB 4
#define NT 256
#define NN 48
#define NF 4
#define NH 64
#define NK 4
#define NE 192
#define NLH 512
#define NC 8
#define NG 1024          // B*T
#define KH 256           // K*H
#define SEQD 3072        // N*H
#define G4 2048          // 4*LH
#define LSTM_NBLK 64

__device__ __forceinline__ float bf2f(u16 v) {
  union { u32 u; float f; } c; c.u = ((u32)v) << 16; return c.f;
}
__device__ __forceinline__ u16 f2bf(float f) {
  union { float f; u32 u; } c; c.f = f;
  u32 r = c.u + 0x7FFFu + ((c.u >> 16) & 1u);
  return (u16)(r >> 16);
}
__device__ __forceinline__ u32 fbits(float f) { union { float f; u32 u; } c; c.f = f; return c.u; }
__device__ __forceinline__ float bitsf(u32 u) { union { u32 u; float f; } c; c.u = u; return c.f; }

// ---------------- kernel 0: CSR build (by dst) ----------------
__global__ void setup_kernel(const int* __restrict__ ei, int* __restrict__ coff,
                             int* __restrict__ ceid)
{
  if (threadIdx.x == 0 && blockIdx.x == 0) {
    int cnt[NN];
    for (int n = 0; n < NN; ++n) cnt[n] = 0;
    for (int e = 0; e < NE; ++e) cnt[ei[NE + e]]++;
    coff[0] = 0;
    for (int n = 0; n < NN; ++n) coff[n + 1] = coff[n] + cnt[n];
    int pos[NN];
    for (int n = 0; n < NN; ++n) pos[n] = coff[n];
    for (int e = 0; e < NE; ++e) { int d = ei[NE + e]; ceid[pos[d]++] = e; }
  }
}

// ---------------- kernel 0b: transpose Wl2/Wr2 -> [out][in] (f32) -----------
__global__ void transpose_kernel(const float* __restrict__ Wl2, const float* __restrict__ Wr2,
                                 float* __restrict__ WlT, float* __restrict__ WrT)
{
  int id0 = blockIdx.x * 256 + threadIdx.x;
  for (int rep = 0; rep < 2; ++rep) {
    int id = id0 + rep * 32768;               // id = o*256 + i
    int o = id >> 8, i = id & 255;
    WlT[id] = Wl2[i * 256 + o];
    WrT[id] = Wr2[i * 256 + o];
  }
}

// ---------------- kernel 1: fused GATv2 layer1+layer2 (one block per graph) --
__global__ __launch_bounds__(256) void gat_fused_kernel(
    const float* __restrict__ x, const int* __restrict__ ei,
    const int* __restrict__ coff, const int* __restrict__ ceid,
    const float* __restrict__ Wl1, const float* __restrict__ Wr1,
    const float* __restrict__ att1, const float* __restrict__ b1,
    const float* __restrict__ WlT, const float* __restrict__ WrT,
    const float* __restrict__ att2, const float* __restrict__ b2,
    float* __restrict__ h2)
{
  __shared__ float sA[NN * KH];          // 48KB: h1 (f32), later xl|xr (bf16)
  __shared__ float sWl1[NF * KH], sWr1[NF * KH];   // 4KB + 4KB
  __shared__ float satt[KH];             // att1 then att2
  __shared__ float sbias[KH];            // b1 then b2
  __shared__ float sx[NN * NF];          // 768B
  __shared__ float esc[NE * NK];         // 3KB
  __shared__ int soff[NN + 1];           // 196B
  __shared__ u16 seid[NE], ssrc[NE], sdst[NE];   // 3*384B

  const int tid = threadIdx.x;
  const int g = blockIdx.x;

#pragma unroll
  for (int rep = 0; rep < 4; ++rep) {
    int idx = rep * 256 + tid;
    sWl1[idx] = Wl1[idx];
    sWr1[idx] = Wr1[idx];
  }
  satt[tid] = att1[tid];
  sbias[tid] = b1[tid];
  if (tid < NN * NF) sx[tid] = x[(size_t)g * (NN * NF) + tid];
  if (tid < NE) {
    ssrc[tid] = (u16)ei[tid];
    sdst[tid] = (u16)ei[NE + tid];
    seid[tid] = (u16)ceid[tid];
  }
  if (tid < NN + 1) soff[tid] = coff[tid];
  __syncthreads();

  // ---- layer-1 edge scores ----
  for (int task = tid; task < NE * NK; task += 256) {
    int e = task >> 2, k = task & 3;
    int s = ssrc[e], d = sdst[e];
    float xs0 = sx[s * 4 + 0], xs1 = sx[s * 4 + 1], xs2 = sx[s * 4 + 2], xs3 = sx[s * 4 + 3];
    float xd0 = sx[d * 4 + 0], xd1 = sx[d * 4 + 1], xd2 = sx[d * 4 + 2], xd3 = sx[d * 4 + 3];
    float acc = 0.f;
    int ob = k * 64;
    for (int h = 0; h < 64; ++h) {
      int o = ob + h;
      float xl = fmaf(xs3, sWl1[768 + o], fmaf(xs2, sWl1[512 + o],
                 fmaf(xs1, sWl1[256 + o], xs0 * sWl1[o])));
      float xr = fmaf(xd3, sWr1[768 + o], fmaf(xd2, sWr1[512 + o],
                 fmaf(xd1, sWr1[256 + o], xd0 * sWr1[o])));
      float tv = xl + xr;
      tv = tv > 0.f ? tv : 0.2f * tv;
      acc = fmaf(tv, satt[o], acc);
    }
    esc[e * 4 + k] = acc;
  }
  __syncthreads();

  // ---- layer-1 softmax per (n,k) ----
  if (tid < NN * NK) {
    int n = tid >> 2, k = tid & 3;
    int e0 = soff[n], e1 = soff[n + 1];
    if (e1 > e0) {
      float m = -1e30f;
      for (int j = e0; j < e1; ++j) m = fmaxf(m, esc[seid[j] * 4 + k]);
      float den = 0.f;
      for (int j = e0; j < e1; ++j) {
        float pv = expf(esc[seid[j] * 4 + k] - m);
        esc[seid[j] * 4 + k] = pv;
        den += pv;
      }
      float inv = 1.f / (den + 1e-16f);
      for (int j = e0; j < e1; ++j) esc[seid[j] * 4 + k] *= inv;
    }
  }
  __syncthreads();

  // ---- layer-1 aggregate -> h1 into sA (f32); reload att2 ----
  satt[tid] = att2[tid];
  {
    int o = tid, k = o >> 6;
    float w0 = sWl1[o], w1 = sWl1[256 + o], w2 = sWl1[512 + o], w3 = sWl1[768 + o];
    for (int n = 0; n < NN; ++n) {
      int e0 = soff[n], e1 = soff[n + 1];
      float acc = 0.f;
      for (int j = e0; j < e1; ++j) {
        int e = seid[j];
        int s = ssrc[e];
        float xl = fmaf(sx[s * 4 + 3], w3, fmaf(sx[s * 4 + 2], w2,
                   fmaf(sx[s * 4 + 1], w1, sx[s * 4 + 0] * w0)));
        acc = fmaf(esc[e * 4 + k], xl, acc);
      }
      float ov = acc + sbias[o];
      sA[n * KH + o] = fmaxf(ov, 0.f);
    }
  }
  __syncthreads();
  if (tid < NH) sbias[tid] = b2[tid];

  // ---- layer-2 transforms: thread owns output column o = tid ----
  float axl[NN], axr[NN];
#pragma unroll
  for (int n = 0; n < NN; ++n) { axl[n] = 0.f; axr[n] = 0.f; }
  {
    const float* wlr = WlT + (size_t)tid * 256;
    const float* wrr = WrT + (size_t)tid * 256;
    for (int ic = 0; ic < 32; ++ic) {
      const float4* wl4 = (const float4*)(wlr + ic * 8);
      const float4* wr4 = (const float4*)(wrr + ic * 8);
      float4 la = wl4[0], lb = wl4[1], ra = wr4[0], rb = wr4[1];
      float wl[8] = {la.x, la.y, la.z, la.w, lb.x, lb.y, lb.z, lb.w};
      float wr[8] = {ra.x, ra.y, ra.z, ra.w, rb.x, rb.y, rb.z, rb.w};
#pragma unroll
      for (int n = 0; n < NN; ++n) {
        const float4* hp = (const float4*)&sA[n * 256 + ic * 8];
        float4 ha = hp[0], hb = hp[1];
        float hv[8] = {ha.x, ha.y, ha.z, ha.w, hb.x, hb.y, hb.z, hb.w};
#pragma unroll
        for (int q = 0; q < 8; ++q) {
          axl[n] = fmaf(hv[q], wl[q], axl[n]);
          axr[n] = fmaf(hv[q], wr[q], axr[n]);
        }
      }
    }
  }
  __syncthreads();
  u16* xlb = (u16*)sA;
  u16* xrb = xlb + NN * KH;
#pragma unroll
  for (int n = 0; n < NN; ++n) {
    xlb[n * 256 + tid] = f2bf(axl[n]);
    xrb[n * 256 + tid] = f2bf(axr[n]);
  }
  __syncthreads();

  // ---- layer-2 edge scores ----
  for (int task = tid; task < NE * NK; task += 256) {
    int e = task >> 2, k = task & 3;
    int s = ssrc[e], d = sdst[e];
    const u16* xls = xlb + s * 256 + k * 64;
    const u16* xrd = xrb + d * 256 + k * 64;
    const float* ap = satt + k * 64;
    float acc = 0.f;
    for (int h = 0; h < 64; ++h) {
      float tv = bf2f(xls[h]) + bf2f(xrd[h]);
      tv = tv > 0.f ? tv : 0.2f * tv;
      acc = fmaf(tv, ap[h], acc);
    }
    esc[e * 4 + k] = acc;
  }
  __syncthreads();

  // ---- layer-2 softmax ----
  if (tid < NN * NK) {
    int n = tid >> 2, k = tid & 3;
    int e0 = soff[n], e1 = soff[n + 1];
    if (e1 > e0) {
      float m = -1e30f;
      for (int j = e0; j < e1; ++j) m = fmaxf(m, esc[seid[j] * 4 + k]);
      float den = 0.f;
      for (int j = e0; j < e1; ++j) {
        float pv = expf(esc[seid[j] * 4 + k] - m);
        esc[seid[j] * 4 + k] = pv;
        den += pv;
      }
      float inv = 1.f / (den + 1e-16f);
      for (int j = e0; j < e1; ++j) esc[seid[j] * 4 + k] *= inv;
    }
  }
  __syncthreads();

  // ---- layer-2 aggregate, mean over k, +bias, relu -> h2 (f32) ----
  for (int task = tid; task < NN * NH; task += 256) {
    int n = task >> 6, h = task & 63;
    int e0 = soff[n], e1 = soff[n + 1];
    float acc = 0.f;
    for (int j = e0; j < e1; ++j) {
      int e = seid[j];
      int s = ssrc[e];
      const u16* xls = xlb + s * 256 + h;
#pragma unroll
      for (int k = 0; k < 4; ++k)
        acc = fmaf(esc[e * 4 + k], bf2f(xls[k * 64]), acc);
    }
    float ov = fmaf(acc, 0.25f, sbias[h]);
    h2[(size_t)g * SEQD + task] = fmaxf(ov, 0.f);
  }
}

// ---------------- kernel 3: xw = seq @ W_ih^T + (b_ih+b_hh), all f32 --------
__global__ __launch_bounds__(256) void xw_kernel(const float* __restrict__ h2,
                                                 const float* __restrict__ Wih,
                                                 const float* __restrict__ bih,
                                                 const float* __restrict__ bhh,
                                                 float* __restrict__ xw)
{
  __shared__ float sseq[96 * 64];   // [i][g]
  __shared__ float sw[96 * 64];     // [i][r]
  const int tid = threadIdx.x;
  const int gt = blockIdx.x & 15;
  const int rt = blockIdx.x >> 4;
  const int g0 = gt * 64, r0 = rt * 64;
  const int r = tid & 63, gsub = tid >> 6;
  const int R = r0 + r;
  const int lane = tid & 63, qi = tid >> 6;
  float acc[16];
#pragma unroll
  for (int j = 0; j < 16; ++j) acc[j] = 0.f;

  for (int ic = 0; ic < 32; ++ic) {
    __syncthreads();
    {
      const float* src = h2 + (size_t)(g0 + lane) * SEQD + ic * 96 + qi * 24;
#pragma unroll
      for (int q = 0; q < 24; ++q) sseq[(qi * 24 + q) * 64 + lane] = src[q];
    }
    {
      const float* wsrc = Wih + (size_t)(r0 + lane) * SEQD + ic * 96 + qi * 24;
#pragma unroll
      for (int q = 0; q < 24; ++q) sw[(qi * 24 + q) * 64 + lane] = wsrc[q];
    }
    __syncthreads();
    for (int i = 0; i < 96; ++i) {
      float wv = sw[i * 64 + r];
      const float4* sp = (const float4*)&sseq[i * 64 + gsub * 16];
      float4 s0 = sp[0], s1 = sp[1], s2 = sp[2], s3 = sp[3];
      float sv[16] = {s0.x, s0.y, s0.z, s0.w, s1.x, s1.y, s1.z, s1.w,
                      s2.x, s2.y, s2.z, s2.w, s3.x, s3.y, s3.z, s3.w};
#pragma unroll
      for (int j = 0; j < 16; ++j) acc[j] = fmaf(sv[j], wv, acc[j]);
    }
  }
  const float bias = bih[R] + bhh[R];
#pragma unroll
  for (int j = 0; j < 16; ++j) {
    int g = g0 + gsub * 16 + j;
    xw[(size_t)g * G4 + R] = acc[j] + bias;
  }
}

// ---------------- kernel 4: wave-autonomous persistent LSTM + FC ------------
// 64 blocks x 256 threads; wave w of block blk owns hidden units
// u = blk*8 + 2w + {0,1}, all 4 batches. No LDS, no __syncthreads in the loop.
// Each lane polls 32 stamped pairs (k-slice of 8 x 4 batches) -> the wave holds
// the FULL h; 256 FMA; reduce-scatter butterfly (masks 1,2,4,8,16 then 32);
// combo at lane l: c4..c0 = l0..l4, c = g*8 + du*4 + b; gather 4 gates with 2
// shuffles; all lanes redundantly compute the cell; 8 writer lanes store.
__global__ __launch_bounds__(256) void lstm_kernel(const float* __restrict__ xw,
                                                   const float* __restrict__ Whh,
                                                   const float* __restrict__ fcw,
                                                   const float* __restrict__ fcb,
                                                   u64* pairs,
                                                   float* __restrict__ out)
{
  const int tid = threadIdx.x;
  const int blk = blockIdx.x;
  const int lane = tid & 63;
  const int w = tid >> 6;
  const int l0 = lane & 1, l1 = (lane >> 1) & 1, l2 = (lane >> 2) & 1;
  const int l3 = (lane >> 3) & 1, l4 = (lane >> 4) & 1;
  const int myg = 2 * l0 + l1;              // post-reduction gate index
  const int du  = l2;                       // post-reduction unit offset
  const int bb  = 2 * l3 + l4;              // post-reduction batch
  const int unit = blk * 8 + 2 * w + du;    // global hidden unit
  const bool writer = ((lane & 3) == 0) && (lane < 32);

  // weights: 8 rows (g*2+duw), k-slice lane*8..+8
  float wreg[8][8];
#pragma unroll
  for (int gg = 0; gg < 4; ++gg)
#pragma unroll
    for (int duw = 0; duw < 2; ++duw) {
      int Rr = gg * 512 + blk * 8 + 2 * w + duw;
      const float4* wp = (const float4*)(Whh + (size_t)Rr * NLH + lane * 8);
      float4 va = wp[0], vb = wp[1];
      int r = gg * 2 + duw;
      wreg[r][0] = va.x; wreg[r][1] = va.y; wreg[r][2] = va.z; wreg[r][3] = va.w;
      wreg[r][4] = vb.x; wreg[r][5] = vb.y; wreg[r][6] = vb.z; wreg[r][7] = vb.w;
    }

  float cst = 0.f;                          // cell state for (du,bb), dup x8
  if (writer)
    __hip_atomic_store(&pairs[0 * (NB * NLH) + bb * NLH + unit], 0ULL,
                       __ATOMIC_RELAXED, __HIP_MEMORY_SCOPE_AGENT);

  for (int s = 0; s < NT; ++s) {
    // xw for my post-reduction combo (independent of h: issue before poll)
    float xwv = xw[(size_t)(bb * NT + s) * G4 + myg * 512 + unit];

    // poll-with-data: full h_s (parity s&1), 32 pairs per lane
    u64 v[32];
    {
      u64* pb = pairs + (size_t)(s & 1) * (NB * NLH);
      while (true) {
#pragma unroll
        for (int b = 0; b < NB; ++b)
#pragma unroll
          for (int j = 0; j < 8; ++j)
            v[b * 8 + j] = __hip_atomic_load(&pb[b * NLH + lane * 8 + j],
                                             __ATOMIC_RELAXED, __HIP_MEMORY_SCOPE_AGENT);
        int mn = 0x7fffffff;
#pragma unroll
        for (int q = 0; q < 32; ++q) mn = min(mn, (int)(u32)(v[q] >> 32));
        if (__all(mn >= s)) break;
      }
    }

    // a[c], c = r*4 + b, r = g*2 + duw
    float a[32];
#pragma unroll
    for (int c = 0; c < 32; ++c) a[c] = 0.f;
#pragma unroll
    for (int b = 0; b < NB; ++b)
#pragma unroll
      for (int j = 0; j < 8; ++j) {
        float hv = bitsf((u32)v[b * 8 + j]);
#pragma unroll
        for (int r = 0; r < 8; ++r)
          a[r * 4 + b] = fmaf(wreg[r][j], hv, a[r * 4 + b]);
      }

    // reduce-scatter: masks 1,2,4,8,16 (halving), then xor-32 completes
    {
      bool hi = (lane & 1);
#pragma unroll
      for (int i = 0; i < 16; ++i) {
        float send = hi ? a[i] : a[i + 16];
        float keep = hi ? a[i + 16] : a[i];
        a[i] = keep + __shfl_xor(send, 1, 64);
      }
      hi = (lane & 2);
#pragma unroll
      for (int i = 0; i < 8; ++i) {
        float send = hi ? a[i] : a[i + 8];
        float keep = hi ? a[i + 8] : a[i];
        a[i] = keep + __shfl_xor(send, 2, 64);
      }
      hi = (lane & 4);
#pragma unroll
      for (int i = 0; i < 4; ++i) {
        float send = hi ? a[i] : a[i + 4];
        float keep = hi ? a[i + 4] : a[i];
        a[i] = keep + __shfl_xor(send, 4, 64);
      }
      hi = (lane & 8);
#pragma unroll
      for (int i = 0; i < 2; ++i) {
        float send = hi ? a[i] : a[i + 2];
        float keep = hi ? a[i + 2] : a[i];
        a[i] = keep + __shfl_xor(send, 8, 64);
      }
      hi = (lane & 16);
      {
        float send = hi ? a[0] : a[1];
        float keep = hi ? a[1] : a[0];
        a[0] = keep + __shfl_xor(send, 16, 64);
      }
      a[0] += __shfl_xor(a[0], 32, 64);
    }
    float pre = a[0] + xwv;                 // gate(myg) for (du,bb)

    // gather the 4 gates of (du,bb): arr[d] = gate (myg ^ d)
    float x1 = __shfl_xor(pre, 1, 64);      // gate myg^2
    float x2 = __shfl_xor(pre, 2, 64);      // gate myg^1
    float x3 = __shfl_xor(x1, 2, 64);       // gate myg^3
    float arr0 = pre, arr1 = x2, arr2 = x1, arr3 = x3;
    // gate[G] = arr[myg ^ G]
    float gi, gf, gG, gO;
    {
      int k0 = myg;          gi = (k0 & 1) ? ((k0 & 2) ? arr3 : arr1) : ((k0 & 2) ? arr2 : arr0);
      int k1 = myg ^ 1;      gf = (k1 & 1) ? ((k1 & 2) ? arr3 : arr1) : ((k1 & 2) ? arr2 : arr0);
      int k2 = myg ^ 2;      gG = (k2 & 1) ? ((k2 & 2) ? arr3 : arr1) : ((k2 & 2) ? arr2 : arr0);
      int k3 = myg ^ 3;      gO = (k3 & 1) ? ((k3 & 2) ? arr3 : arr1) : ((k3 & 2) ? arr2 : arr0);
    }
    float si = 1.f / (1.f + expf(-gi));
    float sf = 1.f / (1.f + expf(-gf));
    float so = 1.f / (1.f + expf(-gO));
    float cn = fmaf(sf, cst, si * tanhf(gG));
    float hn = so * tanhf(cn);
    cst = cn;
    if (writer) {
      u64 pk = ((u64)(u32)(s + 1) << 32) | (u64)fbits(hn);
      __hip_atomic_store(&pairs[(size_t)((s + 1) & 1) * (NB * NLH) + bb * NLH + unit],
                         pk, __ATOMIC_RELAXED, __HIP_MEMORY_SCOPE_AGENT);
    }
  }

  // ---- FC epilogue: block 0, wave 0 only; register-only via reduce-scatter --
  if (blk == 0 && w == 0) {
    u64 v[32];
    {
      u64* pb = pairs + (size_t)(NT & 1) * (NB * NLH);
      while (true) {
#pragma unroll
        for (int b = 0; b < NB; ++b)
#pragma unroll
          for (int j = 0; j < 8; ++j)
            v[b * 8 + j] = __hip_atomic_load(&pb[b * NLH + lane * 8 + j],
                                             __ATOMIC_RELAXED, __HIP_MEMORY_SCOPE_AGENT);
        int mn = 0x7fffffff;
#pragma unroll
        for (int q = 0; q < 32; ++q) mn = min(mn, (int)(u32)(v[q] >> 32));
        if (__all(mn >= NT)) break;
      }
    }
    // fw[cc][j] = fcw[cc*512 + lane*8 + j]
    float fw[8][8];
#pragma unroll
    for (int cc = 0; cc < 8; ++cc) {
      const float4* fp = (const float4*)(fcw + (size_t)cc * NLH + lane * 8);
      float4 va = fp[0], vb = fp[1];
      fw[cc][0] = va.x; fw[cc][1] = va.y; fw[cc][2] = va.z; fw[cc][3] = va.w;
      fw[cc][4] = vb.x; fw[cc][5] = vb.y; fw[cc][6] = vb.z; fw[cc][7] = vb.w;
    }
    float a[32];                            // c = cc*4 + b
#pragma unroll
    for (int c = 0; c < 32; ++c) a[c] = 0.f;
#pragma unroll
    for (int b = 0; b < NB; ++b)
#pragma unroll
      for (int j = 0; j < 8; ++j) {
        float hv = bitsf((u32)v[b * 8 + j]);
#pragma unroll
        for (int cc = 0; cc < 8; ++cc)
          a[cc * 4 + b] = fmaf(fw[cc][j], hv, a[cc * 4 + b]);
      }
    {
      bool hi = (lane & 1);
#pragma unroll
      for (int i = 0; i < 16; ++i) {
        float send = hi ? a[i] : a[i + 16];
        float keep = hi ? a[i + 16] : a[i];
        a[i] = keep + __shfl_xor(send, 1, 64);
      }
      hi = (lane & 2);
#pragma unroll
      for (int i = 0; i < 8; ++i) {
        float send = hi ? a[i] : a[i + 8];
        float keep = hi ? a[i + 8] : a[i];
        a[i] = keep + __shfl_xor(send, 2, 64);
      }
      hi = (lane & 4);
#pragma unroll
      for (int i = 0; i < 4; ++i) {
        float send = hi ? a[i] : a[i + 4];
        float keep = hi ? a[i + 4] : a[i];
        a[i] = keep + __shfl_xor(send, 4, 64);
      }
      hi = (lane & 8);
#pragma unroll
      for (int i = 0; i < 2; ++i) {
        float send = hi ? a[i] : a[i + 2];
        float keep = hi ? a[i + 2] : a[i];
        a[i] = keep + __shfl_xor(send, 8, 64);
      }
      hi = (lane & 16);
      {
        float send = hi ? a[0] : a[1];
        float keep = hi ? a[1] : a[0];
        a[0] = keep + __shfl_xor(send, 16, 64);
      }
      a[0] += __shfl_xor(a[0], 32, 64);
    }
    // lane combo: cc = 4*l0 + 2*l1 + l2, b = 2*l3 + l4; dup at lane^32
    if (lane < 32) {
      int cc = 4 * l0 + 2 * l1 + l2;
      int b = bb;
      out[b * NC + cc] = a[0] + fcb[cc];
    }
  }
}

// ---------------- host ----------------
extern "C" void kernel_launch(void* const* d_in, const int* in_sizes, int n_in,
                              void* d_out, int out_size, void* d_ws, size_t ws_size,
                              hipStream_t stream)
{
  (void)in_sizes; (void)n_in; (void)out_size; (void)ws_size;
  const float* x    = (const float*)d_in[0];
  const int*   ei   = (const int*)d_in[1];
  const float* Wl1  = (const float*)d_in[2];
  const float* Wr1  = (const float*)d_in[3];
  const float* att1 = (const float*)d_in[4];
  const float* b1   = (const float*)d_in[5];
  const float* Wl2  = (const float*)d_in[6];
  const float* Wr2  = (const float*)d_in[7];
  const float* att2 = (const float*)d_in[8];
  const float* b2   = (const float*)d_in[9];
  const float* Wih  = (const float*)d_in[10];
  const float* Whh  = (const float*)d_in[11];
  const float* bih  = (const float*)d_in[12];
  const float* bhh  = (const float*)d_in[13];
  const float* fcw  = (const float*)d_in[14];
  const float* fcb  = (const float*)d_in[15];

  char* ws = (char*)d_ws;
  int* csr_off = (int*)(ws + 0);                    // 49 ints
  int* csr_eid = (int*)(ws + 256);                  // 192 ints -> ends 1024
  u64* pairs   = (u64*)(ws + 1024);                 // 2*2048*8B = 32KB -> 33792
  float* WlT   = (float*)(ws + 40960);              // 256 KB -> 303104
  float* WrT   = (float*)(ws + 303104);             // 256 KB -> 565248
  float* h2    = (float*)(ws + 565248);             // 12 MB  -> 13148160
  float* xwb   = (float*)(ws + 13148160);           // 8 MB   -> 21536768
  float* outp  = (float*)d_out;

  setup_kernel<<<1, 64, 0, stream>>>(ei, csr_off, csr_eid);
  transpose_kernel<<<128, 256, 0, stream>>>(Wl2, Wr2, WlT, WrT);
  gat_fused_kernel<<<NG, 256, 0, stream>>>(x, ei, csr_off, csr_eid,
                                           Wl1, Wr1, att1, b1,
                                           WlT, WrT, att2, b2, h2);
  xw_kernel<<<512, 256, 0, stream>>>(h2, Wih, bih, bhh, xwb);
  lstm_kernel<<<LSTM_NBLK, 256, 0, stream>>>(xwb, Whh, fcw, fcb, pairs, outp);
}

// Round 8
// 1641.234 us; speedup vs baseline: 1.8599x; 1.8599x over previous
//
#include <hip/hip_runtime.h>
#include <math.h>

typedef unsigned short u16;
typedef unsigned int u32;
typedef unsigned long long u64;

// dims
#define NB 4
#define NT 256
#define NN 48
#define NF 4
#define NH 64
#define NK 4
#define NE 192
#define NLH 512
#define NC 8
#define NG 1024          // B*T
#define KH 256           // K*H
#define SEQD 3072        // N*H
#define G4 2048          // 4*LH
#define LSTM_NBLK 64

__device__ __forceinline__ float bf2f(u16 v) {
  union { u32 u; float f; } c; c.u = ((u32)v) << 16; return c.f;
}
__device__ __forceinline__ u16 f2bf(float f) {
  union { float f; u32 u; } c; c.f = f;
  u32 r = c.u + 0x7FFFu + ((c.u >> 16) & 1u);
  return (u16)(r >> 16);
}
__device__ __forceinline__ u32 fbits(float f) { union { float f; u32 u; } c; c.f = f; return c.u; }
__device__ __forceinline__ float bitsf(u32 u) { union { u32 u; float f; } c; c.u = u; return c.f; }

// ---------------- kernel 0: CSR build (by dst) ----------------
__global__ void setup_kernel(const int* __restrict__ ei, int* __restrict__ coff,
                             int* __restrict__ ceid)
{
  if (threadIdx.x == 0 && blockIdx.x == 0) {
    int cnt[NN];
    for (int n = 0; n < NN; ++n) cnt[n] = 0;
    for (int e = 0; e < NE; ++e) cnt[ei[NE + e]]++;
    coff[0] = 0;
    for (int n = 0; n < NN; ++n) coff[n + 1] = coff[n] + cnt[n];
    int pos[NN];
    for (int n = 0; n < NN; ++n) pos[n] = coff[n];
    for (int e = 0; e < NE; ++e) { int d = ei[NE + e]; ceid[pos[d]++] = e; }
  }
}

// ---------------- kernel 0b: transpose Wl2/Wr2 -> [out][in] (f32) -----------
__global__ void transpose_kernel(const float* __restrict__ Wl2, const float* __restrict__ Wr2,
                                 float* __restrict__ WlT, float* __restrict__ WrT)
{
  int id0 = blockIdx.x * 256 + threadIdx.x;
  for (int rep = 0; rep < 2; ++rep) {
    int id = id0 + rep * 32768;               // id = o*256 + i
    int o = id >> 8, i = id & 255;
    WlT[id] = Wl2[i * 256 + o];
    WrT[id] = Wr2[i * 256 + o];
  }
}

// ---------------- kernel 1: fused GATv2 layer1+layer2 (one block per graph) --
__global__ __launch_bounds__(256) void gat_fused_kernel(
    const float* __restrict__ x, const int* __restrict__ ei,
    const int* __restrict__ coff, const int* __restrict__ ceid,
    const float* __restrict__ Wl1, const float* __restrict__ Wr1,
    const float* __restrict__ att1, const float* __restrict__ b1,
    const float* __restrict__ WlT, const float* __restrict__ WrT,
    const float* __restrict__ att2, const float* __restrict__ b2,
    float* __restrict__ h2)
{
  __shared__ float sA[NN * KH];          // 48KB: h1 (f32), later xl|xr (bf16)
  __shared__ float sWl1[NF * KH], sWr1[NF * KH];   // 4KB + 4KB
  __shared__ float satt[KH];             // att1 then att2
  __shared__ float sbias[KH];            // b1 then b2
  __shared__ float sx[NN * NF];          // 768B
  __shared__ float esc[NE * NK];         // 3KB
  __shared__ int soff[NN + 1];           // 196B
  __shared__ u16 seid[NE], ssrc[NE], sdst[NE];   // 3*384B

  const int tid = threadIdx.x;
  const int g = blockIdx.x;

#pragma unroll
  for (int rep = 0; rep < 4; ++rep) {
    int idx = rep * 256 + tid;
    sWl1[idx] = Wl1[idx];
    sWr1[idx] = Wr1[idx];
  }
  satt[tid] = att1[tid];
  sbias[tid] = b1[tid];
  if (tid < NN * NF) sx[tid] = x[(size_t)g * (NN * NF) + tid];
  if (tid < NE) {
    ssrc[tid] = (u16)ei[tid];
    sdst[tid] = (u16)ei[NE + tid];
    seid[tid] = (u16)ceid[tid];
  }
  if (tid < NN + 1) soff[tid] = coff[tid];
  __syncthreads();

  // ---- layer-1 edge scores ----
  for (int task = tid; task < NE * NK; task += 256) {
    int e = task >> 2, k = task & 3;
    int s = ssrc[e], d = sdst[e];
    float xs0 = sx[s * 4 + 0], xs1 = sx[s * 4 + 1], xs2 = sx[s * 4 + 2], xs3 = sx[s * 4 + 3];
    float xd0 = sx[d * 4 + 0], xd1 = sx[d * 4 + 1], xd2 = sx[d * 4 + 2], xd3 = sx[d * 4 + 3];
    float acc = 0.f;
    int ob = k * 64;
    for (int h = 0; h < 64; ++h) {
      int o = ob + h;
      float xl = fmaf(xs3, sWl1[768 + o], fmaf(xs2, sWl1[512 + o],
                 fmaf(xs1, sWl1[256 + o], xs0 * sWl1[o])));
      float xr = fmaf(xd3, sWr1[768 + o], fmaf(xd2, sWr1[512 + o],
                 fmaf(xd1, sWr1[256 + o], xd0 * sWr1[o])));
      float tv = xl + xr;
      tv = tv > 0.f ? tv : 0.2f * tv;
      acc = fmaf(tv, satt[o], acc);
    }
    esc[e * 4 + k] = acc;
  }
  __syncthreads();

  // ---- layer-1 softmax per (n,k) ----
  if (tid < NN * NK) {
    int n = tid >> 2, k = tid & 3;
    int e0 = soff[n], e1 = soff[n + 1];
    if (e1 > e0) {
      float m = -1e30f;
      for (int j = e0; j < e1; ++j) m = fmaxf(m, esc[seid[j] * 4 + k]);
      float den = 0.f;
      for (int j = e0; j < e1; ++j) {
        float pv = expf(esc[seid[j] * 4 + k] - m);
        esc[seid[j] * 4 + k] = pv;
        den += pv;
      }
      float inv = 1.f / (den + 1e-16f);
      for (int j = e0; j < e1; ++j) esc[seid[j] * 4 + k] *= inv;
    }
  }
  __syncthreads();

  // ---- layer-1 aggregate -> h1 into sA (f32); reload att2 ----
  satt[tid] = att2[tid];
  {
    int o = tid, k = o >> 6;
    float w0 = sWl1[o], w1 = sWl1[256 + o], w2 = sWl1[512 + o], w3 = sWl1[768 + o];
    for (int n = 0; n < NN; ++n) {
      int e0 = soff[n], e1 = soff[n + 1];
      float acc = 0.f;
      for (int j = e0; j < e1; ++j) {
        int e = seid[j];
        int s = ssrc[e];
        float xl = fmaf(sx[s * 4 + 3], w3, fmaf(sx[s * 4 + 2], w2,
                   fmaf(sx[s * 4 + 1], w1, sx[s * 4 + 0] * w0)));
        acc = fmaf(esc[e * 4 + k], xl, acc);
      }
      float ov = acc + sbias[o];
      sA[n * KH + o] = fmaxf(ov, 0.f);
    }
  }
  __syncthreads();
  if (tid < NH) sbias[tid] = b2[tid];

  // ---- layer-2 transforms: thread owns output column o = tid ----
  float axl[NN], axr[NN];
#pragma unroll
  for (int n = 0; n < NN; ++n) { axl[n] = 0.f; axr[n] = 0.f; }
  {
    const float* wlr = WlT + (size_t)tid * 256;
    const float* wrr = WrT + (size_t)tid * 256;
    for (int ic = 0; ic < 32; ++ic) {
      const float4* wl4 = (const float4*)(wlr + ic * 8);
      const float4* wr4 = (const float4*)(wrr + ic * 8);
      float4 la = wl4[0], lb = wl4[1], ra = wr4[0], rb = wr4[1];
      float wl[8] = {la.x, la.y, la.z, la.w, lb.x, lb.y, lb.z, lb.w};
      float wr[8] = {ra.x, ra.y, ra.z, ra.w, rb.x, rb.y, rb.z, rb.w};
#pragma unroll
      for (int n = 0; n < NN; ++n) {
        const float4* hp = (const float4*)&sA[n * 256 + ic * 8];
        float4 ha = hp[0], hb = hp[1];
        float hv[8] = {ha.x, ha.y, ha.z, ha.w, hb.x, hb.y, hb.z, hb.w};
#pragma unroll
        for (int q = 0; q < 8; ++q) {
          axl[n] = fmaf(hv[q], wl[q], axl[n]);
          axr[n] = fmaf(hv[q], wr[q], axr[n]);
        }
      }
    }
  }
  __syncthreads();
  u16* xlb = (u16*)sA;
  u16* xrb = xlb + NN * KH;
#pragma unroll
  for (int n = 0; n < NN; ++n) {
    xlb[n * 256 + tid] = f2bf(axl[n]);
    xrb[n * 256 + tid] = f2bf(axr[n]);
  }
  __syncthreads();

  // ---- layer-2 edge scores ----
  for (int task = tid; task < NE * NK; task += 256) {
    int e = task >> 2, k = task & 3;
    int s = ssrc[e], d = sdst[e];
    const u16* xls = xlb + s * 256 + k * 64;
    const u16* xrd = xrb + d * 256 + k * 64;
    const float* ap = satt + k * 64;
    float acc = 0.f;
    for (int h = 0; h < 64; ++h) {
      float tv = bf2f(xls[h]) + bf2f(xrd[h]);
      tv = tv > 0.f ? tv : 0.2f * tv;
      acc = fmaf(tv, ap[h], acc);
    }
    esc[e * 4 + k] = acc;
  }
  __syncthreads();

  // ---- layer-2 softmax ----
  if (tid < NN * NK) {
    int n = tid >> 2, k = tid & 3;
    int e0 = soff[n], e1 = soff[n + 1];
    if (e1 > e0) {
      float m = -1e30f;
      for (int j = e0; j < e1; ++j) m = fmaxf(m, esc[seid[j] * 4 + k]);
      float den = 0.f;
      for (int j = e0; j < e1; ++j) {
        float pv = expf(esc[seid[j] * 4 + k] - m);
        esc[seid[j] * 4 + k] = pv;
        den += pv;
      }
      float inv = 1.f / (den + 1e-16f);
      for (int j = e0; j < e1; ++j) esc[seid[j] * 4 + k] *= inv;
    }
  }
  __syncthreads();

  // ---- layer-2 aggregate, mean over k, +bias, relu -> h2 (f32) ----
  for (int task = tid; task < NN * NH; task += 256) {
    int n = task >> 6, h = task & 63;
    int e0 = soff[n], e1 = soff[n + 1];
    float acc = 0.f;
    for (int j = e0; j < e1; ++j) {
      int e = seid[j];
      int s = ssrc[e];
      const u16* xls = xlb + s * 256 + h;
#pragma unroll
      for (int k = 0; k < 4; ++k)
        acc = fmaf(esc[e * 4 + k], bf2f(xls[k * 64]), acc);
    }
    float ov = fmaf(acc, 0.25f, sbias[h]);
    h2[(size_t)g * SEQD + task] = fmaxf(ov, 0.f);
  }
}

// ---------------- kernel 3: xw = seq @ W_ih^T + (b_ih+b_hh) -----------------
// Register-tiled: 256 blocks (16 gt x 16 rt), tile 64g x 128r, 256 threads,
// thread tile 4g x 8r. Per k: 3 ds_read_b128 + 32 FMA -> VALU-bound (the old
// version was LDS-pipe-bound at 16 FMA / 68 B).
#define XW_KC 32
__global__ __launch_bounds__(256) void xw_kernel(const float* __restrict__ h2,
                                                 const float* __restrict__ Wih,
                                                 const float* __restrict__ bih,
                                                 const float* __restrict__ bhh,
                                                 float* __restrict__ xw)
{
  __shared__ float sseq[XW_KC * 64];    // [k][g] 8KB
  __shared__ float sw[XW_KC * 128];     // [k][r] 16KB
  const int tid = threadIdx.x;
  const int gt = blockIdx.x & 15;
  const int rt = blockIdx.x >> 4;
  const int g0 = gt * 64, r0 = rt * 128;
  // staging roles
  const int gi = tid & 63,  kqa = tid >> 6;   // sseq: kqa<4, 8 k each
  const int ri = tid & 127, kqb = tid >> 7;   // sw:   kqb<2, 16 k each
  // compute roles: thread tile 4g x 8r
  const int tg = tid >> 4, tr = tid & 15;

  float acc[4][8];
#pragma unroll
  for (int a = 0; a < 4; ++a)
#pragma unroll
    for (int b = 0; b < 8; ++b) acc[a][b] = 0.f;

  for (int kc = 0; kc < SEQD; kc += XW_KC) {
    __syncthreads();
    {
      const float4* src = (const float4*)(h2 + (size_t)(g0 + gi) * SEQD + kc + kqa * 8);
      float4 v0 = src[0], v1 = src[1];
      int kb = kqa * 8;
      sseq[(kb + 0) * 64 + gi] = v0.x; sseq[(kb + 1) * 64 + gi] = v0.y;
      sseq[(kb + 2) * 64 + gi] = v0.z; sseq[(kb + 3) * 64 + gi] = v0.w;
      sseq[(kb + 4) * 64 + gi] = v1.x; sseq[(kb + 5) * 64 + gi] = v1.y;
      sseq[(kb + 6) * 64 + gi] = v1.z; sseq[(kb + 7) * 64 + gi] = v1.w;
    }
    {
      const float4* src = (const float4*)(Wih + (size_t)(r0 + ri) * SEQD + kc + kqb * 16);
      float4 v0 = src[0], v1 = src[1], v2 = src[2], v3 = src[3];
      int kb = kqb * 16;
      sw[(kb + 0) * 128 + ri] = v0.x;  sw[(kb + 1) * 128 + ri] = v0.y;
      sw[(kb + 2) * 128 + ri] = v0.z;  sw[(kb + 3) * 128 + ri] = v0.w;
      sw[(kb + 4) * 128 + ri] = v1.x;  sw[(kb + 5) * 128 + ri] = v1.y;
      sw[(kb + 6) * 128 + ri] = v1.z;  sw[(kb + 7) * 128 + ri] = v1.w;
      sw[(kb + 8) * 128 + ri] = v2.x;  sw[(kb + 9) * 128 + ri] = v2.y;
      sw[(kb + 10) * 128 + ri] = v2.z; sw[(kb + 11) * 128 + ri] = v2.w;
      sw[(kb + 12) * 128 + ri] = v3.x; sw[(kb + 13) * 128 + ri] = v3.y;
      sw[(kb + 14) * 128 + ri] = v3.z; sw[(kb + 15) * 128 + ri] = v3.w;
    }
    __syncthreads();
#pragma unroll 4
    for (int k = 0; k < XW_KC; ++k) {
      float4 sg = *(const float4*)&sseq[k * 64 + tg * 4];
      float4 ra = *(const float4*)&sw[k * 128 + tr * 8];
      float4 rb = *(const float4*)&sw[k * 128 + tr * 8 + 4];
      float gv[4] = {sg.x, sg.y, sg.z, sg.w};
      float rv[8] = {ra.x, ra.y, ra.z, ra.w, rb.x, rb.y, rb.z, rb.w};
#pragma unroll
      for (int a = 0; a < 4; ++a)
#pragma unroll
        for (int b = 0; b < 8; ++b)
          acc[a][b] = fmaf(gv[a], rv[b], acc[a][b]);
    }
  }
  float bias[8];
#pragma unroll
  for (int b = 0; b < 8; ++b) {
    int R = r0 + tr * 8 + b;
    bias[b] = bih[R] + bhh[R];
  }
#pragma unroll
  for (int a = 0; a < 4; ++a) {
    float* dst = xw + (size_t)(g0 + tg * 4 + a) * G4 + r0 + tr * 8;
    float4 o0 = {acc[a][0] + bias[0], acc[a][1] + bias[1],
                 acc[a][2] + bias[2], acc[a][3] + bias[3]};
    float4 o1 = {acc[a][4] + bias[4], acc[a][5] + bias[5],
                 acc[a][6] + bias[6], acc[a][7] + bias[7]};
    *(float4*)dst = o0;
    *(float4*)(dst + 4) = o1;
  }
}

// ---------------- kernel 4: persistent LSTM + FC, self-validating pairs -----
// (round-6 version: segment-owned polling, LDS reduce, Whh in VGPRs)
__global__ __launch_bounds__(256) void lstm_kernel(const float* __restrict__ xw,
                                                   const float* __restrict__ Whh,
                                                   const float* __restrict__ fcw,
                                                   const float* __restrict__ fcb,
                                                   u64* pairs,
                                                   float* __restrict__ out)
{
  __shared__ float hlds[NB * NLH];     // 8KB
  __shared__ float part[8][32][4];
  __shared__ float gv[32][4];
  __shared__ float clds[8][4];
  __shared__ float fcpart[32][8];

  const int tid = threadIdx.x;
  const int blk = blockIdx.x;
  const int r32 = tid & 31, p = tid >> 5;
  const int lane = tid & 63, w = tid >> 6;
  const int R = (r32 >> 3) * NLH + blk * 8 + (r32 & 7);  // gate row owned

  float wreg[64];                       // Whh row R, segment p*64..p*64+63
  {
    const float4* wsrc = (const float4*)(Whh + (size_t)R * NLH + p * 64);
#pragma unroll
    for (int q = 0; q < 16; ++q) {
      float4 v = wsrc[q];
      wreg[4 * q + 0] = v.x; wreg[4 * q + 1] = v.y;
      wreg[4 * q + 2] = v.z; wreg[4 * q + 3] = v.w;
    }
  }
  // h_0 = 0 with stamp 0 (ws poison 0xAAAA.. has negative stamp = not-ready)
  if (tid < 32) {
    int u = tid & 7, b = tid >> 3;
    clds[u][b] = 0.f;
    __hip_atomic_store(&pairs[0 * (NB * NLH) + b * NLH + blk * 8 + u], 0ULL,
                       __ATOMIC_RELAXED, __HIP_MEMORY_SCOPE_AGENT);
  }

  for (int s = 0; s < NT; ++s) {
    float myxw = 0.f;
    if (tid < 128) {
      int rrx = tid & 31, b = tid >> 5;
      int Rx = (rrx >> 3) * NLH + blk * 8 + (rrx & 7);
      myxw = xw[(size_t)(b * NT + s) * G4 + Rx];
    }
    // poll-with-data: wave w fetches its 128 units x 4 batches, 8 pairs/lane
    {
      u64* pb = pairs + (size_t)(s & 1) * (NB * NLH);
      const int u0 = w * 128 + lane, u1 = u0 + 64;
      u64 v[8];
      while (true) {
#pragma unroll
        for (int b = 0; b < NB; ++b) {
          v[2 * b]     = __hip_atomic_load(&pb[b * NLH + u0],
                                           __ATOMIC_RELAXED, __HIP_MEMORY_SCOPE_AGENT);
          v[2 * b + 1] = __hip_atomic_load(&pb[b * NLH + u1],
                                           __ATOMIC_RELAXED, __HIP_MEMORY_SCOPE_AGENT);
        }
        int mn = 0x7fffffff;
#pragma unroll
        for (int q = 0; q < 8; ++q) mn = min(mn, (int)(u32)(v[q] >> 32));
        if (__all(mn >= s)) break;
      }
#pragma unroll
      for (int b = 0; b < NB; ++b) {
        hlds[b * NLH + u0] = bitsf((u32)v[2 * b]);
        hlds[b * NLH + u1] = bitsf((u32)v[2 * b + 1]);
      }
    }
    // no block barrier: wave w reads only hlds range it just wrote

    float a0 = 0.f, a1 = 0.f, a2 = 0.f, a3 = 0.f;
    const float* h0 = &hlds[0 * NLH + p * 64];
    const float* h1p = &hlds[1 * NLH + p * 64];
    const float* h2p = &hlds[2 * NLH + p * 64];
    const float* h3p = &hlds[3 * NLH + p * 64];
#pragma unroll
    for (int j = 0; j < 16; ++j) {
      float w0 = wreg[4 * j], w1 = wreg[4 * j + 1], w2 = wreg[4 * j + 2], w3 = wreg[4 * j + 3];
      float4 v0 = *(const float4*)(h0 + 4 * j);
      float4 v1 = *(const float4*)(h1p + 4 * j);
      float4 v2 = *(const float4*)(h2p + 4 * j);
      float4 v3 = *(const float4*)(h3p + 4 * j);
      a0 = fmaf(v0.w, w3, fmaf(v0.z, w2, fmaf(v0.y, w1, fmaf(v0.x, w0, a0))));
      a1 = fmaf(v1.w, w3, fmaf(v1.z, w2, fmaf(v1.y, w1, fmaf(v1.x, w0, a1))));
      a2 = fmaf(v2.w, w3, fmaf(v2.z, w2, fmaf(v2.y, w1, fmaf(v2.x, w0, a2))));
      a3 = fmaf(v3.w, w3, fmaf(v3.z, w2, fmaf(v3.y, w1, fmaf(v3.x, w0, a3))));
    }
    part[p][r32][0] = a0; part[p][r32][1] = a1;
    part[p][r32][2] = a2; part[p][r32][3] = a3;
    __syncthreads();                                  // barrier A
    if (tid < 128) {
      int rrx = tid & 31, b = tid >> 5;
      float sum = myxw;
#pragma unroll
      for (int pp = 0; pp < 8; ++pp) sum += part[pp][rrx][b];
      gv[rrx][b] = sum;
    }
    __syncthreads();                                  // barrier B
    if (tid < 32) {
      int u = tid & 7, b = tid >> 3;
      float gi = gv[0 + u][b], gf = gv[8 + u][b], gg = gv[16 + u][b], go = gv[24 + u][b];
      float si = 1.f / (1.f + expf(-gi));
      float sf = 1.f / (1.f + expf(-gf));
      float so = 1.f / (1.f + expf(-go));
      float cn = fmaf(sf, clds[u][b], si * tanhf(gg));
      float hn = so * tanhf(cn);
      clds[u][b] = cn;
      u64 pk = ((u64)(u32)(s + 1) << 32) | (u64)fbits(hn);
      __hip_atomic_store(&pairs[(size_t)((s + 1) & 1) * (NB * NLH) + b * NLH + blk * 8 + u],
                         pk, __ATOMIC_RELAXED, __HIP_MEMORY_SCOPE_AGENT);
    }
  }

  // FC on block 0; final h_NT is in parity NT&1 = 0 with stamp NT
  if (blk == 0) {
    {
      u64* pb = pairs + (size_t)(NT & 1) * (NB * NLH);
      const int u0 = w * 128 + lane, u1 = u0 + 64;
      u64 v[8];
      while (true) {
#pragma unroll
        for (int b = 0; b < NB; ++b) {
          v[2 * b]     = __hip_atomic_load(&pb[b * NLH + u0],
                                           __ATOMIC_RELAXED, __HIP_MEMORY_SCOPE_AGENT);
          v[2 * b + 1] = __hip_atomic_load(&pb[b * NLH + u1],
                                           __ATOMIC_RELAXED, __HIP_MEMORY_SCOPE_AGENT);
        }
        int mn = 0x7fffffff;
#pragma unroll
        for (int q = 0; q < 8; ++q) mn = min(mn, (int)(u32)(v[q] >> 32));
        if (__all(mn >= NT)) break;
      }
#pragma unroll
      for (int b = 0; b < NB; ++b) {
        hlds[b * NLH + u0] = bitsf((u32)v[2 * b]);
        hlds[b * NLH + u1] = bitsf((u32)v[2 * b + 1]);
      }
    }
    __syncthreads();   // FC reads across all waves' staged segments
    int pr = tid >> 3, l = tid & 7;
    int b = pr >> 3, cc = pr & 7;
    const float* hf = hlds + b * NLH;
    float a = 0.f;
    int base = cc * NLH + l * 64;
    for (int j = 0; j < 64; ++j) a = fmaf(hf[l * 64 + j], fcw[base + j], a);
    fcpart[pr][l] = a;
    __syncthreads();
    if (tid < 32) {
      float s = fcb[tid & 7];
#pragma unroll
      for (int l2 = 0; l2 < 8; ++l2) s += fcpart[tid][l2];
      out[tid] = s;
    }
  }
}

// ---------------- host ----------------
extern "C" void kernel_launch(void* const* d_in, const int* in_sizes, int n_in,
                              void* d_out, int out_size, void* d_ws, size_t ws_size,
                              hipStream_t stream)
{
  (void)in_sizes; (void)n_in; (void)out_size; (void)ws_size;
  const float* x    = (const float*)d_in[0];
  const int*   ei   = (const int*)d_in[1];
  const float* Wl1  = (const float*)d_in[2];
  const float* Wr1  = (const float*)d_in[3];
  const float* att1 = (const float*)d_in[4];
  const float* b1   = (const float*)d_in[5];
  const float* Wl2  = (const float*)d_in[6];
  const float* Wr2  = (const float*)d_in[7];
  const float* att2 = (const float*)d_in[8];
  const float* b2   = (const float*)d_in[9];
  const float* Wih  = (const float*)d_in[10];
  const float* Whh  = (const float*)d_in[11];
  const float* bih  = (const float*)d_in[12];
  const float* bhh  = (const float*)d_in[13];
  const float* fcw  = (const float*)d_in[14];
  const float* fcb  = (const float*)d_in[15];

  char* ws = (char*)d_ws;
  int* csr_off = (int*)(ws + 0);                    // 49 ints
  int* csr_eid = (int*)(ws + 256);                  // 192 ints -> ends 1024
  u64* pairs   = (u64*)(ws + 1024);                 // 2*2048*8B = 32KB -> 33792
  float* WlT   = (float*)(ws + 40960);              // 256 KB -> 303104
  float* WrT   = (float*)(ws + 303104);             // 256 KB -> 565248
  float* h2    = (float*)(ws + 565248);             // 12 MB  -> 13148160
  float* xwb   = (float*)(ws + 13148160);           // 8 MB   -> 21536768
  float* outp  = (float*)d_out;

  setup_kernel<<<1, 64, 0, stream>>>(ei, csr_off, csr_eid);
  transpose_kernel<<<128, 256, 0, stream>>>(Wl2, Wr2, WlT, WrT);
  gat_fused_kernel<<<NG, 256, 0, stream>>>(x, ei, csr_off, csr_eid,
                                           Wl1, Wr1, att1, b1,
                                           WlT, WrT, att2, b2, h2);
  xw_kernel<<<256, 256, 0, stream>>>(h2, Wih, bih, bhh, xwb);
  lstm_kernel<<<LSTM_NBLK, 256, 0, stream>>>(xwb, Whh, fcw, fcb, pairs, outp);
}

// Round 9
// 1464.405 us; speedup vs baseline: 2.0845x; 1.1208x over previous
//
#include <hip/hip_runtime.h>
#include <math.h>

typedef unsigned short u16;
typedef unsigned int u32;
typedef unsigned long long u64;

// dims
#define NB 4
#define NT 256
#define NN 48
#define NF 4
#define NH 64
#define NK 4
#define NE 192
#define NLH 512
#define NC 8
#define NG 1024          // B*T
#define KH 256           // K*H
#define SEQD 3072        // N*H
#define G4 2048          // 4*LH
#define LSTM_NBLK 64
#define SLOTF 6144       // per-graph union slot, in floats (24576 B)

typedef __attribute__((ext_vector_type(8))) short bf16x8;
typedef __attribute__((ext_vector_type(4))) float f32x4;

__device__ __forceinline__ float bf2f(u16 v) {
  union { u32 u; float f; } c; c.u = ((u32)v) << 16; return c.f;
}
__device__ __forceinline__ u16 f2bf(float f) {
  union { float f; u32 u; } c; c.f = f;
  u32 r = c.u + 0x7FFFu + ((c.u >> 16) & 1u);
  return (u16)(r >> 16);
}
__device__ __forceinline__ u32 fbits(float f) { union { float f; u32 u; } c; c.f = f; return c.u; }
__device__ __forceinline__ float bitsf(u32 u) { union { u32 u; float f; } c; c.u = u; return c.f; }

// ---------------- kernel 0: CSR build (by dst) ----------------
__global__ void setup_kernel(const int* __restrict__ ei, int* __restrict__ coff,
                             int* __restrict__ ceid)
{
  if (threadIdx.x == 0 && blockIdx.x == 0) {
    int cnt[NN];
    for (int n = 0; n < NN; ++n) cnt[n] = 0;
    for (int e = 0; e < NE; ++e) cnt[ei[NE + e]]++;
    coff[0] = 0;
    for (int n = 0; n < NN; ++n) coff[n + 1] = coff[n] + cnt[n];
    int pos[NN];
    for (int n = 0; n < NN; ++n) pos[n] = coff[n];
    for (int e = 0; e < NE; ++e) { int d = ei[NE + e]; ceid[pos[d]++] = e; }
  }
}

// ---------------- kernel 0b: build WTc bf16 [n=512][k=256] ------------------
// n<256 -> Wl2[k][n]; n>=256 -> Wr2[k][n-256]
__global__ void wtc_kernel(const float* __restrict__ Wl2, const float* __restrict__ Wr2,
                           u16* __restrict__ WTc)
{
  int id0 = blockIdx.x * 256 + threadIdx.x;
#pragma unroll
  for (int rep = 0; rep < 4; ++rep) {
    int id = id0 + rep * 32768;               // id = n*256 + k
    int n = id >> 8, k = id & 255;
    float v = (n < 256) ? Wl2[k * 256 + n] : Wr2[k * 256 + (n - 256)];
    WTc[id] = f2bf(v);
  }
}

// ---------------- kernel 1: GATv2 layer 1 (per-graph) -> h1 bf16 ------------
__global__ __launch_bounds__(256) void gat1_kernel(
    const float* __restrict__ x, const int* __restrict__ ei,
    const int* __restrict__ coff, const int* __restrict__ ceid,
    const float* __restrict__ Wl1, const float* __restrict__ Wr1,
    const float* __restrict__ att1, const float* __restrict__ b1,
    u16* __restrict__ uni)
{
  __shared__ float sWl1[NF * KH], sWr1[NF * KH];   // 4KB + 4KB
  __shared__ float satt[KH];
  __shared__ float sbias[KH];
  __shared__ float sx[NN * NF];
  __shared__ float esc[NE * NK];
  __shared__ int soff[NN + 1];
  __shared__ u16 seid[NE], ssrc[NE], sdst[NE];

  const int tid = threadIdx.x;
  const int g = blockIdx.x;

#pragma unroll
  for (int rep = 0; rep < 4; ++rep) {
    int idx = rep * 256 + tid;
    sWl1[idx] = Wl1[idx];
    sWr1[idx] = Wr1[idx];
  }
  satt[tid] = att1[tid];
  sbias[tid] = b1[tid];
  if (tid < NN * NF) sx[tid] = x[(size_t)g * (NN * NF) + tid];
  if (tid < NE) {
    ssrc[tid] = (u16)ei[tid];
    sdst[tid] = (u16)ei[NE + tid];
    seid[tid] = (u16)ceid[tid];
  }
  if (tid < NN + 1) soff[tid] = coff[tid];
  __syncthreads();

  // edge scores
  for (int task = tid; task < NE * NK; task += 256) {
    int e = task >> 2, k = task & 3;
    int s = ssrc[e], d = sdst[e];
    float xs0 = sx[s * 4 + 0], xs1 = sx[s * 4 + 1], xs2 = sx[s * 4 + 2], xs3 = sx[s * 4 + 3];
    float xd0 = sx[d * 4 + 0], xd1 = sx[d * 4 + 1], xd2 = sx[d * 4 + 2], xd3 = sx[d * 4 + 3];
    float acc = 0.f;
    int ob = k * 64;
    for (int h = 0; h < 64; ++h) {
      int o = ob + h;
      float xl = fmaf(xs3, sWl1[768 + o], fmaf(xs2, sWl1[512 + o],
                 fmaf(xs1, sWl1[256 + o], xs0 * sWl1[o])));
      float xr = fmaf(xd3, sWr1[768 + o], fmaf(xd2, sWr1[512 + o],
                 fmaf(xd1, sWr1[256 + o], xd0 * sWr1[o])));
      float tv = xl + xr;
      tv = tv > 0.f ? tv : 0.2f * tv;
      acc = fmaf(tv, satt[o], acc);
    }
    esc[e * 4 + k] = acc;
  }
  __syncthreads();

  // softmax per (n,k)
  if (tid < NN * NK) {
    int n = tid >> 2, k = tid & 3;
    int e0 = soff[n], e1 = soff[n + 1];
    if (e1 > e0) {
      float m = -1e30f;
      for (int j = e0; j < e1; ++j) m = fmaxf(m, esc[seid[j] * 4 + k]);
      float den = 0.f;
      for (int j = e0; j < e1; ++j) {
        float pv = expf(esc[seid[j] * 4 + k] - m);
        esc[seid[j] * 4 + k] = pv;
        den += pv;
      }
      float inv = 1.f / (den + 1e-16f);
      for (int j = e0; j < e1; ++j) esc[seid[j] * 4 + k] *= inv;
    }
  }
  __syncthreads();

  // aggregate -> relu(h1) bf16 to global slot
  {
    u16* h1g = uni + (size_t)g * (2 * SLOTF);
    int o = tid, k = o >> 6;
    float w0 = sWl1[o], w1 = sWl1[256 + o], w2 = sWl1[512 + o], w3 = sWl1[768 + o];
    for (int n = 0; n < NN; ++n) {
      int e0 = soff[n], e1 = soff[n + 1];
      float acc = 0.f;
      for (int j = e0; j < e1; ++j) {
        int e = seid[j];
        int s = ssrc[e];
        float xl = fmaf(sx[s * 4 + 3], w3, fmaf(sx[s * 4 + 2], w2,
                   fmaf(sx[s * 4 + 1], w1, sx[s * 4 + 0] * w0)));
        acc = fmaf(esc[e * 4 + k], xl, acc);
      }
      float ov = acc + sbias[o];
      h1g[n * KH + o] = f2bf(fmaxf(ov, 0.f));
    }
  }
}

// ---------------- kernel 2: GATv2 layer 2 (per-graph, MFMA) -----------------
// xl|xr = h1(48x256 bf16) @ WTc^T via mfma_f32_16x16x32_bf16, results in LDS;
// then edges/softmax/aggregate -> h2 f32 overwrites the same uni slot.
__global__ __launch_bounds__(256) void gat2_kernel(
    u16* __restrict__ uni, const u16* __restrict__ WTc,
    const float* __restrict__ att2, const float* __restrict__ b2,
    const int* __restrict__ ei, const int* __restrict__ coff,
    const int* __restrict__ ceid)
{
  __shared__ u16 xlds[NN * 512];        // 48KB: xl (cols 0-255) | xr (256-511)
  __shared__ float esc[NE * NK];        // 3KB
  __shared__ float satt[KH];            // 1KB
  __shared__ float sbias[NH];           // 256B
  __shared__ int soff[NN + 1];
  __shared__ u16 seid[NE], ssrc[NE], sdst[NE];

  const int tid = threadIdx.x;
  const int g = blockIdx.x;
  const int lane = tid & 63, wv = tid >> 6;
  const int l15 = lane & 15, q = lane >> 4;

  satt[tid] = att2[tid];
  if (tid < NH) sbias[tid] = b2[tid];
  if (tid < NE) {
    ssrc[tid] = (u16)ei[tid];
    sdst[tid] = (u16)ei[NE + tid];
    seid[tid] = (u16)ceid[tid];
  }
  if (tid < NN + 1) soff[tid] = coff[tid];

  // ---- MFMA GEMM: A frags (h1) into VGPRs ----
  const u16* h1g = uni + (size_t)g * (2 * SLOTF);
  bf16x8 afr[3][8];
#pragma unroll
  for (int mt = 0; mt < 3; ++mt)
#pragma unroll
    for (int kt = 0; kt < 8; ++kt)
      afr[mt][kt] = *(const bf16x8*)(h1g + (mt * 16 + l15) * KH + kt * 32 + q * 8);

  // wave wv owns n-tiles [wv*8, wv*8+8)
#pragma unroll
  for (int t = 0; t < 8; ++t) {
    int n0 = (wv * 8 + t) * 16;
    const u16* bcol = WTc + (size_t)(n0 + l15) * KH + q * 8;
    f32x4 acc0 = {0.f, 0.f, 0.f, 0.f}, acc1 = acc0, acc2 = acc0;
#pragma unroll
    for (int kt = 0; kt < 8; ++kt) {
      bf16x8 bfr = *(const bf16x8*)(bcol + kt * 32);
      acc0 = __builtin_amdgcn_mfma_f32_16x16x32_bf16(afr[0][kt], bfr, acc0, 0, 0, 0);
      acc1 = __builtin_amdgcn_mfma_f32_16x16x32_bf16(afr[1][kt], bfr, acc1, 0, 0, 0);
      acc2 = __builtin_amdgcn_mfma_f32_16x16x32_bf16(afr[2][kt], bfr, acc2, 0, 0, 0);
    }
    // C/D: col = lane&15, row = quad*4 + reg
#pragma unroll
    for (int r = 0; r < 4; ++r) {
      int rw = q * 4 + r;
      xlds[(0 * 16 + rw) * 512 + n0 + l15] = f2bf(acc0[r]);
      xlds[(1 * 16 + rw) * 512 + n0 + l15] = f2bf(acc1[r]);
      xlds[(2 * 16 + rw) * 512 + n0 + l15] = f2bf(acc2[r]);
    }
  }
  __syncthreads();

  // ---- edge scores ----
  for (int task = tid; task < NE * NK; task += 256) {
    int e = task >> 2, k = task & 3;
    int s = ssrc[e], d = sdst[e];
    const u16* xls = xlds + s * 512 + k * 64;
    const u16* xrd = xlds + d * 512 + 256 + k * 64;
    const float* ap = satt + k * 64;
    float acc = 0.f;
    for (int h = 0; h < 64; ++h) {
      float tv = bf2f(xls[h]) + bf2f(xrd[h]);
      tv = tv > 0.f ? tv : 0.2f * tv;
      acc = fmaf(tv, ap[h], acc);
    }
    esc[e * 4 + k] = acc;
  }
  __syncthreads();

  // ---- softmax ----
  if (tid < NN * NK) {
    int n = tid >> 2, k = tid & 3;
    int e0 = soff[n], e1 = soff[n + 1];
    if (e1 > e0) {
      float m = -1e30f;
      for (int j = e0; j < e1; ++j) m = fmaxf(m, esc[seid[j] * 4 + k]);
      float den = 0.f;
      for (int j = e0; j < e1; ++j) {
        float pv = expf(esc[seid[j] * 4 + k] - m);
        esc[seid[j] * 4 + k] = pv;
        den += pv;
      }
      float inv = 1.f / (den + 1e-16f);
      for (int j = e0; j < e1; ++j) esc[seid[j] * 4 + k] *= inv;
    }
  }
  __syncthreads();

  // ---- aggregate, mean over k, +bias, relu -> h2 f32 (overwrites own slot) --
  {
    float* h2g = (float*)(uni + (size_t)g * (2 * SLOTF));
    for (int task = tid; task < NN * NH; task += 256) {
      int n = task >> 6, h = task & 63;
      int e0 = soff[n], e1 = soff[n + 1];
      float acc = 0.f;
      for (int j = e0; j < e1; ++j) {
        int e = seid[j];
        int s = ssrc[e];
        const u16* xls = xlds + s * 512 + h;
#pragma unroll
        for (int k = 0; k < 4; ++k)
          acc = fmaf(esc[e * 4 + k], bf2f(xls[k * 64]), acc);
      }
      float ov = fmaf(acc, 0.25f, sbias[h]);
      h2g[task] = fmaxf(ov, 0.f);
    }
  }
}

// ---------------- kernel 3: xw = seq @ W_ih^T + (b_ih+b_hh) -----------------
// Register-tiled: 256 blocks (16 gt x 16 rt), tile 64g x 128r, 256 threads,
// thread tile 4g x 8r. h2 rows live in uni slots with stride SLOTF floats.
#define XW_KC 32
__global__ __launch_bounds__(256) void xw_kernel(const float* __restrict__ h2b,
                                                 const float* __restrict__ Wih,
                                                 const float* __restrict__ bih,
                                                 const float* __restrict__ bhh,
                                                 float* __restrict__ xw)
{
  __shared__ float sseq[XW_KC * 64];    // [k][g] 8KB
  __shared__ float sw[XW_KC * 128];     // [k][r] 16KB
  const int tid = threadIdx.x;
  const int gt = blockIdx.x & 15;
  const int rt = blockIdx.x >> 4;
  const int g0 = gt * 64, r0 = rt * 128;
  const int gi = tid & 63,  kqa = tid >> 6;   // sseq: kqa<4, 8 k each
  const int ri = tid & 127, kqb = tid >> 7;   // sw:   kqb<2, 16 k each
  const int tg = tid >> 4, tr = tid & 15;

  float acc[4][8];
#pragma unroll
  for (int a = 0; a < 4; ++a)
#pragma unroll
    for (int b = 0; b < 8; ++b) acc[a][b] = 0.f;

  for (int kc = 0; kc < SEQD; kc += XW_KC) {
    __syncthreads();
    {
      const float4* src = (const float4*)(h2b + (size_t)(g0 + gi) * SLOTF + kc + kqa * 8);
      float4 v0 = src[0], v1 = src[1];
      int kb = kqa * 8;
      sseq[(kb + 0) * 64 + gi] = v0.x; sseq[(kb + 1) * 64 + gi] = v0.y;
      sseq[(kb + 2) * 64 + gi] = v0.z; sseq[(kb + 3) * 64 + gi] = v0.w;
      sseq[(kb + 4) * 64 + gi] = v1.x; sseq[(kb + 5) * 64 + gi] = v1.y;
      sseq[(kb + 6) * 64 + gi] = v1.z; sseq[(kb + 7) * 64 + gi] = v1.w;
    }
    {
      const float4* src = (const float4*)(Wih + (size_t)(r0 + ri) * SEQD + kc + kqb * 16);
      float4 v0 = src[0], v1 = src[1], v2 = src[2], v3 = src[3];
      int kb = kqb * 16;
      sw[(kb + 0) * 128 + ri] = v0.x;  sw[(kb + 1) * 128 + ri] = v0.y;
      sw[(kb + 2) * 128 + ri] = v0.z;  sw[(kb + 3) * 128 + ri] = v0.w;
      sw[(kb + 4) * 128 + ri] = v1.x;  sw[(kb + 5) * 128 + ri] = v1.y;
      sw[(kb + 6) * 128 + ri] = v1.z;  sw[(kb + 7) * 128 + ri] = v1.w;
      sw[(kb + 8) * 128 + ri] = v2.x;  sw[(kb + 9) * 128 + ri] = v2.y;
      sw[(kb + 10) * 128 + ri] = v2.z; sw[(kb + 11) * 128 + ri] = v2.w;
      sw[(kb + 12) * 128 + ri] = v3.x; sw[(kb + 13) * 128 + ri] = v3.y;
      sw[(kb + 14) * 128 + ri] = v3.z; sw[(kb + 15) * 128 + ri] = v3.w;
    }
    __syncthreads();
#pragma unroll 4
    for (int k = 0; k < XW_KC; ++k) {
      float4 sg = *(const float4*)&sseq[k * 64 + tg * 4];
      float4 ra = *(const float4*)&sw[k * 128 + tr * 8];
      float4 rb = *(const float4*)&sw[k * 128 + tr * 8 + 4];
      float gv[4] = {sg.x, sg.y, sg.z, sg.w};
      float rv[8] = {ra.x, ra.y, ra.z, ra.w, rb.x, rb.y, rb.z, rb.w};
#pragma unroll
      for (int a = 0; a < 4; ++a)
#pragma unroll
        for (int b = 0; b < 8; ++b)
          acc[a][b] = fmaf(gv[a], rv[b], acc[a][b]);
    }
  }
  float bias[8];
#pragma unroll
  for (int b = 0; b < 8; ++b) {
    int R = r0 + tr * 8 + b;
    bias[b] = bih[R] + bhh[R];
  }
#pragma unroll
  for (int a = 0; a < 4; ++a) {
    float* dst = xw + (size_t)(g0 + tg * 4 + a) * G4 + r0 + tr * 8;
    float4 o0 = {acc[a][0] + bias[0], acc[a][1] + bias[1],
                 acc[a][2] + bias[2], acc[a][3] + bias[3]};
    float4 o1 = {acc[a][4] + bias[4], acc[a][5] + bias[5],
                 acc[a][6] + bias[6], acc[a][7] + bias[7]};
    *(float4*)dst = o0;
    *(float4*)(dst + 4) = o1;
  }
}

// ---------------- kernel 4: persistent LSTM + FC, self-validating pairs -----
__global__ __launch_bounds__(256) void lstm_kernel(const float* __restrict__ xw,
                                                   const float* __restrict__ Whh,
                                                   const float* __restrict__ fcw,
                                                   const float* __restrict__ fcb,
                                                   u64* pairs,
                                                   float* __restrict__ out)
{
  __shared__ float hlds[NB * NLH];     // 8KB
  __shared__ float part[8][32][4];
  __shared__ float gv[32][4];
  __shared__ float clds[8][4];
  __shared__ float fcpart[32][8];

  const int tid = threadIdx.x;
  const int blk = blockIdx.x;
  const int r32 = tid & 31, p = tid >> 5;
  const int lane = tid & 63, w = tid >> 6;
  const int R = (r32 >> 3) * NLH + blk * 8 + (r32 & 7);

  float wreg[64];
  {
    const float4* wsrc = (const float4*)(Whh + (size_t)R * NLH + p * 64);
#pragma unroll
    for (int q = 0; q < 16; ++q) {
      float4 v = wsrc[q];
      wreg[4 * q + 0] = v.x; wreg[4 * q + 1] = v.y;
      wreg[4 * q + 2] = v.z; wreg[4 * q + 3] = v.w;
    }
  }
  if (tid < 32) {
    int u = tid & 7, b = tid >> 3;
    clds[u][b] = 0.f;
    __hip_atomic_store(&pairs[0 * (NB * NLH) + b * NLH + blk * 8 + u], 0ULL,
                       __ATOMIC_RELAXED, __HIP_MEMORY_SCOPE_AGENT);
  }

  for (int s = 0; s < NT; ++s) {
    float myxw = 0.f;
    if (tid < 128) {
      int rrx = tid & 31, b = tid >> 5;
      int Rx = (rrx >> 3) * NLH + blk * 8 + (rrx & 7);
      myxw = xw[(size_t)(b * NT + s) * G4 + Rx];
    }
    {
      u64* pb = pairs + (size_t)(s & 1) * (NB * NLH);
      const int u0 = w * 128 + lane, u1 = u0 + 64;
      u64 v[8];
      while (true) {
#pragma unroll
        for (int b = 0; b < NB; ++b) {
          v[2 * b]     = __hip_atomic_load(&pb[b * NLH + u0],
                                           __ATOMIC_RELAXED, __HIP_MEMORY_SCOPE_AGENT);
          v[2 * b + 1] = __hip_atomic_load(&pb[b * NLH + u1],
                                           __ATOMIC_RELAXED, __HIP_MEMORY_SCOPE_AGENT);
        }
        int mn = 0x7fffffff;
#pragma unroll
        for (int q = 0; q < 8; ++q) mn = min(mn, (int)(u32)(v[q] >> 32));
        if (__all(mn >= s)) break;
      }
#pragma unroll
      for (int b = 0; b < NB; ++b) {
        hlds[b * NLH + u0] = bitsf((u32)v[2 * b]);
        hlds[b * NLH + u1] = bitsf((u32)v[2 * b + 1]);
      }
    }

    float a0 = 0.f, a1 = 0.f, a2 = 0.f, a3 = 0.f;
    const float* h0 = &hlds[0 * NLH + p * 64];
    const float* h1p = &hlds[1 * NLH + p * 64];
    const float* h2p = &hlds[2 * NLH + p * 64];
    const float* h3p = &hlds[3 * NLH + p * 64];
#pragma unroll
    for (int j = 0; j < 16; ++j) {
      float w0 = wreg[4 * j], w1 = wreg[4 * j + 1], w2 = wreg[4 * j + 2], w3 = wreg[4 * j + 3];
      float4 v0 = *(const float4*)(h0 + 4 * j);
      float4 v1 = *(const float4*)(h1p + 4 * j);
      float4 v2 = *(const float4*)(h2p + 4 * j);
      float4 v3 = *(const float4*)(h3p + 4 * j);
      a0 = fmaf(v0.w, w3, fmaf(v0.z, w2, fmaf(v0.y, w1, fmaf(v0.x, w0, a0))));
      a1 = fmaf(v1.w, w3, fmaf(v1.z, w2, fmaf(v1.y, w1, fmaf(v1.x, w0, a1))));
      a2 = fmaf(v2.w, w3, fmaf(v2.z, w2, fmaf(v2.y, w1, fmaf(v2.x, w0, a2))));
      a3 = fmaf(v3.w, w3, fmaf(v3.z, w2, fmaf(v3.y, w1, fmaf(v3.x, w0, a3))));
    }
    part[p][r32][0] = a0; part[p][r32][1] = a1;
    part[p][r32][2] = a2; part[p][r32][3] = a3;
    __syncthreads();
    if (tid < 128) {
      int rrx = tid & 31, b = tid >> 5;
      float sum = myxw;
#pragma unroll
      for (int pp = 0; pp < 8; ++pp) sum += part[pp][rrx][b];
      gv[rrx][b] = sum;
    }
    __syncthreads();
    if (tid < 32) {
      int u = tid & 7, b = tid >> 3;
      float gi = gv[0 + u][b], gf = gv[8 + u][b], gg = gv[16 + u][b], go = gv[24 + u][b];
      float si = 1.f / (1.f + expf(-gi));
      float sf = 1.f / (1.f + expf(-gf));
      float so = 1.f / (1.f + expf(-go));
      float cn = fmaf(sf, clds[u][b], si * tanhf(gg));
      float hn = so * tanhf(cn);
      clds[u][b] = cn;
      u64 pk = ((u64)(u32)(s + 1) << 32) | (u64)fbits(hn);
      __hip_atomic_store(&pairs[(size_t)((s + 1) & 1) * (NB * NLH) + b * NLH + blk * 8 + u],
                         pk, __ATOMIC_RELAXED, __HIP_MEMORY_SCOPE_AGENT);
    }
  }

  // FC on block 0
  if (blk == 0) {
    {
      u64* pb = pairs + (size_t)(NT & 1) * (NB * NLH);
      const int u0 = w * 128 + lane, u1 = u0 + 64;
      u64 v[8];
      while (true) {
#pragma unroll
        for (int b = 0; b < NB; ++b) {
          v[2 * b]     = __hip_atomic_load(&pb[b * NLH + u0],
                                           __ATOMIC_RELAXED, __HIP_MEMORY_SCOPE_AGENT);
          v[2 * b + 1] = __hip_atomic_load(&pb[b * NLH + u1],
                                           __ATOMIC_RELAXED, __HIP_MEMORY_SCOPE_AGENT);
        }
        int mn = 0x7fffffff;
#pragma unroll
        for (int q = 0; q < 8; ++q) mn = min(mn, (int)(u32)(v[q] >> 32));
        if (__all(mn >= NT)) break;
      }
#pragma unroll
      for (int b = 0; b < NB; ++b) {
        hlds[b * NLH + u0] = bitsf((u32)v[2 * b]);
        hlds[b * NLH + u1] = bitsf((u32)v[2 * b + 1]);
      }
    }
    __syncthreads();
    int pr = tid >> 3, l = tid & 7;
    int b = pr >> 3, cc = pr & 7;
    const float* hf = hlds + b * NLH;
    float a = 0.f;
    int base = cc * NLH + l * 64;
    for (int j = 0; j < 64; ++j) a = fmaf(hf[l * 64 + j], fcw[base + j], a);
    fcpart[pr][l] = a;
    __syncthreads();
    if (tid < 32) {
      float s = fcb[tid & 7];
#pragma unroll
      for (int l2 = 0; l2 < 8; ++l2) s += fcpart[tid][l2];
      out[tid] = s;
    }
  }
}

// ---------------- host ----------------
extern "C" void kernel_launch(void* const* d_in, const int* in_sizes, int n_in,
                              void* d_out, int out_size, void* d_ws, size_t ws_size,
                              hipStream_t stream)
{
  (void)in_sizes; (void)n_in; (void)out_size; (void)ws_size;
  const float* x    = (const float*)d_in[0];
  const int*   ei   = (const int*)d_in[1];
  const float* Wl1  = (const float*)d_in[2];
  const float* Wr1  = (const float*)d_in[3];
  const float* att1 = (const float*)d_in[4];
  const float* b1   = (const float*)d_in[5];
  const float* Wl2  = (const float*)d_in[6];
  const float* Wr2  = (const float*)d_in[7];
  const float* att2 = (const float*)d_in[8];
  const float* b2   = (const float*)d_in[9];
  const float* Wih  = (const float*)d_in[10];
  const float* Whh  = (const float*)d_in[11];
  const float* bih  = (const float*)d_in[12];
  const float* bhh  = (const float*)d_in[13];
  const float* fcw  = (const float*)d_in[14];
  const float* fcb  = (const float*)d_in[15];

  // workspace layout (~32.3 MB)
  char* ws = (char*)d_ws;
  int* csr_off = (int*)(ws + 0);                    // 49 ints
  int* csr_eid = (int*)(ws + 256);                  // 192 ints -> ends 1024
  u64* pairs   = (u64*)(ws + 1024);                 // 32KB -> 33792
  u16* WTc     = (u16*)(ws + 40960);                // 512*256*2 = 262144 -> 303104
  u16* uni     = (u16*)(ws + 303104);               // 1024 slots * 24576B = 24MB -> 25468928
  float* xwb   = (float*)(ws + 25468928);           // 8MB -> 33857536
  float* outp  = (float*)d_out;

  setup_kernel<<<1, 64, 0, stream>>>(ei, csr_off, csr_eid);
  wtc_kernel<<<128, 256, 0, stream>>>(Wl2, Wr2, WTc);
  gat1_kernel<<<NG, 256, 0, stream>>>(x, ei, csr_off, csr_eid,
                                      Wl1, Wr1, att1, b1, uni);
  gat2_kernel<<<NG, 256, 0, stream>>>(uni, WTc, att2, b2, ei, csr_off, csr_eid);
  xw_kernel<<<256, 256, 0, stream>>>((const float*)uni, Wih, bih, bhh, xwb);
  lstm_kernel<<<LSTM_NBLK, 256, 0, stream>>>(xwb, Whh, fcw, fcb, pairs, outp);
}

// Round 10
// 1246.446 us; speedup vs baseline: 2.4490x; 1.1749x over previous
//
#include <hip/hip_runtime.h>
#include <math.h>

typedef unsigned short u16;
typedef unsigned int u32;
typedef unsigned long long u64;

// dims
#define NB 4
#define NT 256
#define NN 48
#define NF 4
#define NH 64
#define NK 4
#define NE 192
#define NLH 512
#define NC 8
#define NG 1024          // B*T
#define KH 256           // K*H
#define SEQD 3072        // N*H
#define G4 2048          // 4*LH
#define LSTM_NBLK 64

typedef __attribute__((ext_vector_type(8))) short bf16x8;
typedef __attribute__((ext_vector_type(4))) float f32x4;

__device__ __forceinline__ float bf2f(u16 v) {
  union { u32 u; float f; } c; c.u = ((u32)v) << 16; return c.f;
}
__device__ __forceinline__ u16 f2bf(float f) {
  union { float f; u32 u; } c; c.f = f;
  u32 r = c.u + 0x7FFFu + ((c.u >> 16) & 1u);
  return (u16)(r >> 16);
}
__device__ __forceinline__ u32 fbits(float f) { union { float f; u32 u; } c; c.f = f; return c.u; }
__device__ __forceinline__ float bitsf(u32 u) { union { u32 u; float f; } c; c.u = u; return c.f; }

// ---------------- kernel 0: CSR build (by dst) ----------------
__global__ void setup_kernel(const int* __restrict__ ei, int* __restrict__ coff,
                             int* __restrict__ ceid)
{
  if (threadIdx.x == 0 && blockIdx.x == 0) {
    int cnt[NN];
    for (int n = 0; n < NN; ++n) cnt[n] = 0;
    for (int e = 0; e < NE; ++e) cnt[ei[NE + e]]++;
    coff[0] = 0;
    for (int n = 0; n < NN; ++n) coff[n + 1] = coff[n] + cnt[n];
    int pos[NN];
    for (int n = 0; n < NN; ++n) pos[n] = coff[n];
    for (int e = 0; e < NE; ++e) { int d = ei[NE + e]; ceid[pos[d]++] = e; }
  }
}

// ---------------- kernel 0b: build WTc bf16 [n=512][k=256] ------------------
__global__ void wtc_kernel(const float* __restrict__ Wl2, const float* __restrict__ Wr2,
                           u16* __restrict__ WTc)
{
  int id0 = blockIdx.x * 256 + threadIdx.x;
#pragma unroll
  for (int rep = 0; rep < 4; ++rep) {
    int id = id0 + rep * 32768;               // id = n*256 + k
    int n = id >> 8, k = id & 255;
    float v = (n < 256) ? Wl2[k * 256 + n] : Wr2[k * 256 + (n - 256)];
    WTc[id] = f2bf(v);
  }
}

// ---------------- kernel 0c: Wih f32 -> bf16 [2048][3072] -------------------
__global__ void wihb_kernel(const float* __restrict__ Wih, u16* __restrict__ WihB)
{
  int id = (blockIdx.x * 256 + threadIdx.x) * 8;
  float4 a = *(const float4*)(Wih + id);
  float4 b = *(const float4*)(Wih + id + 4);
  u16* dst = WihB + id;
  dst[0] = f2bf(a.x); dst[1] = f2bf(a.y); dst[2] = f2bf(a.z); dst[3] = f2bf(a.w);
  dst[4] = f2bf(b.x); dst[5] = f2bf(b.y); dst[6] = f2bf(b.z); dst[7] = f2bf(b.w);
}

// ---------------- kernel 1: fused GATv2 L1+L2 (MFMA mid-section) ------------
// LDS tile xlds[48][512] (bf16) is reused: L1 xl|xr -> (xl | h1) -> L2 xl2|xr2.
__global__ __launch_bounds__(256) void gat_fused_kernel(
    const float* __restrict__ x, const int* __restrict__ ei,
    const int* __restrict__ coff, const int* __restrict__ ceid,
    const float* __restrict__ Wl1, const float* __restrict__ Wr1,
    const float* __restrict__ att1, const float* __restrict__ b1,
    const u16* __restrict__ WTc,
    const float* __restrict__ att2, const float* __restrict__ b2,
    u16* __restrict__ h2b)
{
  __shared__ u16 xlds[NN * 512];        // 48KB
  __shared__ float sWl1[NF * KH], sWr1[NF * KH];   // 8KB
  __shared__ float satt[KH];            // att1 then att2
  __shared__ float sbias[KH];           // b1 then b2
  __shared__ float sx[NN * NF];
  __shared__ float esc[NE * NK];
  __shared__ int soff[NN + 1];
  __shared__ u16 seid[NE], ssrc[NE], sdst[NE];

  const int tid = threadIdx.x;
  const int g = blockIdx.x;
  const int lane = tid & 63, wv = tid >> 6;
  const int l15 = lane & 15, q = lane >> 4;

#pragma unroll
  for (int rep = 0; rep < 4; ++rep) {
    int idx = rep * 256 + tid;
    sWl1[idx] = Wl1[idx];
    sWr1[idx] = Wr1[idx];
  }
  satt[tid] = att1[tid];
  sbias[tid] = b1[tid];
  if (tid < NN * NF) sx[tid] = x[(size_t)g * (NN * NF) + tid];
  if (tid < NE) {
    ssrc[tid] = (u16)ei[tid];
    sdst[tid] = (u16)ei[NE + tid];
    seid[tid] = (u16)ceid[tid];
  }
  if (tid < NN + 1) soff[tid] = coff[tid];
  __syncthreads();

  // ---- L1 transforms once: thread owns column o=tid ----
  {
    float w0 = sWl1[tid], w1 = sWl1[256 + tid], w2 = sWl1[512 + tid], w3 = sWl1[768 + tid];
    float v0 = sWr1[tid], v1 = sWr1[256 + tid], v2 = sWr1[512 + tid], v3 = sWr1[768 + tid];
#pragma unroll 4
    for (int n = 0; n < NN; ++n) {
      float x0 = sx[n * 4 + 0], x1 = sx[n * 4 + 1], x2 = sx[n * 4 + 2], x3 = sx[n * 4 + 3];
      float xl = fmaf(x3, w3, fmaf(x2, w2, fmaf(x1, w1, x0 * w0)));
      float xr = fmaf(x3, v3, fmaf(x2, v2, fmaf(x1, v1, x0 * v0)));
      xlds[n * 512 + tid] = f2bf(xl);
      xlds[n * 512 + 256 + tid] = f2bf(xr);
    }
  }
  __syncthreads();

  // ---- L1 edge scores ----
  for (int task = tid; task < NE * NK; task += 256) {
    int e = task >> 2, k = task & 3;
    int s = ssrc[e], d = sdst[e];
    const u16* xls = xlds + s * 512 + k * 64;
    const u16* xrd = xlds + d * 512 + 256 + k * 64;
    const float* ap = satt + k * 64;
    float acc = 0.f;
    for (int h = 0; h < 64; ++h) {
      float tv = bf2f(xls[h]) + bf2f(xrd[h]);
      tv = tv > 0.f ? tv : 0.2f * tv;
      acc = fmaf(tv, ap[h], acc);
    }
    esc[e * 4 + k] = acc;
  }
  __syncthreads();

  // ---- L1 softmax per (n,k) ----
  if (tid < NN * NK) {
    int n = tid >> 2, k = tid & 3;
    int e0 = soff[n], e1 = soff[n + 1];
    if (e1 > e0) {
      float m = -1e30f;
      for (int j = e0; j < e1; ++j) m = fmaxf(m, esc[seid[j] * 4 + k]);
      float den = 0.f;
      for (int j = e0; j < e1; ++j) {
        float pv = expf(esc[seid[j] * 4 + k] - m);
        esc[seid[j] * 4 + k] = pv;
        den += pv;
      }
      float inv = 1.f / (den + 1e-16f);
      for (int j = e0; j < e1; ++j) esc[seid[j] * 4 + k] *= inv;
    }
  }
  __syncthreads();

  // ---- L1 aggregate -> h1 bf16 into cols 256-511 (xr dead); att2 reload ----
  satt[tid] = att2[tid];
  {
    int o = tid, k = o >> 6;
    for (int n = 0; n < NN; ++n) {
      int e0 = soff[n], e1 = soff[n + 1];
      float acc = 0.f;
      for (int j = e0; j < e1; ++j) {
        int e = seid[j];
        int s = ssrc[e];
        acc = fmaf(esc[e * 4 + k], bf2f(xlds[s * 512 + o]), acc);
      }
      float ov = acc + sbias[o];
      xlds[n * 512 + 256 + o] = f2bf(fmaxf(ov, 0.f));
    }
  }
  __syncthreads();
  if (tid < NH) sbias[tid] = b2[tid];

  // ---- MFMA: A-frags (h1) from LDS into VGPRs ----
  bf16x8 afr[3][8];
#pragma unroll
  for (int mt = 0; mt < 3; ++mt)
#pragma unroll
    for (int kt = 0; kt < 8; ++kt)
      afr[mt][kt] = *(const bf16x8*)(xlds + (mt * 16 + l15) * 512 + 256 + kt * 32 + q * 8);
  __syncthreads();   // all A-frags in regs before outputs overwrite the tile

  // wave wv owns n-tiles [wv*8, wv*8+8)
#pragma unroll
  for (int t = 0; t < 8; ++t) {
    int n0 = (wv * 8 + t) * 16;
    const u16* bcol = WTc + (size_t)(n0 + l15) * KH + q * 8;
    f32x4 acc0 = {0.f, 0.f, 0.f, 0.f}, acc1 = acc0, acc2 = acc0;
#pragma unroll
    for (int kt = 0; kt < 8; ++kt) {
      bf16x8 bfr = *(const bf16x8*)(bcol + kt * 32);
      acc0 = __builtin_amdgcn_mfma_f32_16x16x32_bf16(afr[0][kt], bfr, acc0, 0, 0, 0);
      acc1 = __builtin_amdgcn_mfma_f32_16x16x32_bf16(afr[1][kt], bfr, acc1, 0, 0, 0);
      acc2 = __builtin_amdgcn_mfma_f32_16x16x32_bf16(afr[2][kt], bfr, acc2, 0, 0, 0);
    }
#pragma unroll
    for (int r = 0; r < 4; ++r) {
      int rw = q * 4 + r;
      xlds[(0 * 16 + rw) * 512 + n0 + l15] = f2bf(acc0[r]);
      xlds[(1 * 16 + rw) * 512 + n0 + l15] = f2bf(acc1[r]);
      xlds[(2 * 16 + rw) * 512 + n0 + l15] = f2bf(acc2[r]);
    }
  }
  __syncthreads();

  // ---- L2 edge scores ----
  for (int task = tid; task < NE * NK; task += 256) {
    int e = task >> 2, k = task & 3;
    int s = ssrc[e], d = sdst[e];
    const u16* xls = xlds + s * 512 + k * 64;
    const u16* xrd = xlds + d * 512 + 256 + k * 64;
    const float* ap = satt + k * 64;
    float acc = 0.f;
    for (int h = 0; h < 64; ++h) {
      float tv = bf2f(xls[h]) + bf2f(xrd[h]);
      tv = tv > 0.f ? tv : 0.2f * tv;
      acc = fmaf(tv, ap[h], acc);
    }
    esc[e * 4 + k] = acc;
  }
  __syncthreads();

  // ---- L2 softmax ----
  if (tid < NN * NK) {
    int n = tid >> 2, k = tid & 3;
    int e0 = soff[n], e1 = soff[n + 1];
    if (e1 > e0) {
      float m = -1e30f;
      for (int j = e0; j < e1; ++j) m = fmaxf(m, esc[seid[j] * 4 + k]);
      float den = 0.f;
      for (int j = e0; j < e1; ++j) {
        float pv = expf(esc[seid[j] * 4 + k] - m);
        esc[seid[j] * 4 + k] = pv;
        den += pv;
      }
      float inv = 1.f / (den + 1e-16f);
      for (int j = e0; j < e1; ++j) esc[seid[j] * 4 + k] *= inv;
    }
  }
  __syncthreads();

  // ---- L2 aggregate, mean over k, +bias, relu -> h2 bf16 global ----
  for (int task = tid; task < NN * NH; task += 256) {
    int n = task >> 6, h = task & 63;
    int e0 = soff[n], e1 = soff[n + 1];
    float acc = 0.f;
    for (int j = e0; j < e1; ++j) {
      int e = seid[j];
      int s = ssrc[e];
      const u16* xls = xlds + s * 512 + h;
#pragma unroll
      for (int k = 0; k < 4; ++k)
        acc = fmaf(esc[e * 4 + k], bf2f(xls[k * 64]), acc);
    }
    float ov = fmaf(acc, 0.25f, sbias[h]);
    h2b[(size_t)g * SEQD + task] = f2bf(fmaxf(ov, 0.f));
  }
}

// ---------------- kernel 3: xw = seq @ W_ih^T + bias, bf16 MFMA -------------
// Grid 256 blocks (16 gt x 16 rt), tile M=64 x N=128, 256 threads (4 waves).
// Wave wv owns 2 n-tiles x 4 m-tiles.
__global__ __launch_bounds__(256) void xw_mfma_kernel(const u16* __restrict__ h2b,
                                                      const u16* __restrict__ WihB,
                                                      const float* __restrict__ bih,
                                                      const float* __restrict__ bhh,
                                                      float* __restrict__ xw)
{
  const int tid = threadIdx.x, lane = tid & 63, wv = tid >> 6;
  const int l15 = lane & 15, q = lane >> 4;
  const int gt = blockIdx.x & 15, rt = blockIdx.x >> 4;
  const int g0 = gt * 64, r0 = rt * 128;

  const u16* arow[4];
#pragma unroll
  for (int mt = 0; mt < 4; ++mt)
    arow[mt] = h2b + (size_t)(g0 + mt * 16 + l15) * SEQD + q * 8;
  const u16* brow[2];
  int ncol[2];
#pragma unroll
  for (int tn = 0; tn < 2; ++tn) {
    ncol[tn] = r0 + (wv * 2 + tn) * 16 + l15;
    brow[tn] = WihB + (size_t)ncol[tn] * SEQD + q * 8;
  }

  f32x4 acc[4][2];
#pragma unroll
  for (int mt = 0; mt < 4; ++mt)
#pragma unroll
    for (int tn = 0; tn < 2; ++tn) acc[mt][tn] = (f32x4){0.f, 0.f, 0.f, 0.f};

  for (int kt = 0; kt < SEQD / 32; ++kt) {
    bf16x8 af[4], bfv[2];
#pragma unroll
    for (int mt = 0; mt < 4; ++mt) af[mt] = *(const bf16x8*)(arow[mt] + kt * 32);
#pragma unroll
    for (int tn = 0; tn < 2; ++tn) bfv[tn] = *(const bf16x8*)(brow[tn] + kt * 32);
#pragma unroll
    for (int mt = 0; mt < 4; ++mt)
#pragma unroll
      for (int tn = 0; tn < 2; ++tn)
        acc[mt][tn] = __builtin_amdgcn_mfma_f32_16x16x32_bf16(af[mt], bfv[tn], acc[mt][tn], 0, 0, 0);
  }

#pragma unroll
  for (int tn = 0; tn < 2; ++tn) {
    float bias = bih[ncol[tn]] + bhh[ncol[tn]];
#pragma unroll
    for (int mt = 0; mt < 4; ++mt)
#pragma unroll
      for (int r = 0; r < 4; ++r) {
        int gg = g0 + mt * 16 + q * 4 + r;
        xw[(size_t)gg * G4 + ncol[tn]] = acc[mt][tn][r] + bias;
      }
  }
}

// ---------------- kernel 4: persistent LSTM + FC, self-validating pairs -----
// Single barrier per step; part[] double-buffered by step parity.
__global__ __launch_bounds__(256) void lstm_kernel(const float* __restrict__ xw,
                                                   const float* __restrict__ Whh,
                                                   const float* __restrict__ fcw,
                                                   const float* __restrict__ fcb,
                                                   u64* pairs,
                                                   float* __restrict__ out)
{
  __shared__ float hlds[NB * NLH];     // 8KB
  __shared__ float part[2][8][32][4];  // 8KB, parity-buffered
  __shared__ float clds[8][4];
  __shared__ float fcpart[32][8];

  const int tid = threadIdx.x;
  const int blk = blockIdx.x;
  const int r32 = tid & 31, p = tid >> 5;
  const int lane = tid & 63, w = tid >> 6;
  const int R = (r32 >> 3) * NLH + blk * 8 + (r32 & 7);

  float wreg[64];
  {
    const float4* wsrc = (const float4*)(Whh + (size_t)R * NLH + p * 64);
#pragma unroll
    for (int q = 0; q < 16; ++q) {
      float4 v = wsrc[q];
      wreg[4 * q + 0] = v.x; wreg[4 * q + 1] = v.y;
      wreg[4 * q + 2] = v.z; wreg[4 * q + 3] = v.w;
    }
  }
  if (tid < 32) {
    int u = tid & 7, b = tid >> 3;
    clds[u][b] = 0.f;
    __hip_atomic_store(&pairs[0 * (NB * NLH) + b * NLH + blk * 8 + u], 0ULL,
                       __ATOMIC_RELAXED, __HIP_MEMORY_SCOPE_AGENT);
  }

  for (int s = 0; s < NT; ++s) {
    // gates thread loads its 4 xw rows before the poll (independent of h)
    float myxw[4];
    if (tid < 32) {
      int u = tid & 7, b = tid >> 3;
#pragma unroll
      for (int G = 0; G < 4; ++G)
        myxw[G] = xw[(size_t)(b * NT + s) * G4 + G * 512 + blk * 8 + u];
    }
    // poll-with-data: wave w fetches its 128 units x 4 batches, 8 pairs/lane
    {
      u64* pb = pairs + (size_t)(s & 1) * (NB * NLH);
      const int u0 = w * 128 + lane, u1 = u0 + 64;
      u64 v[8];
      while (true) {
#pragma unroll
        for (int b = 0; b < NB; ++b) {
          v[2 * b]     = __hip_atomic_load(&pb[b * NLH + u0],
                                           __ATOMIC_RELAXED, __HIP_MEMORY_SCOPE_AGENT);
          v[2 * b + 1] = __hip_atomic_load(&pb[b * NLH + u1],
                                           __ATOMIC_RELAXED, __HIP_MEMORY_SCOPE_AGENT);
        }
        int mn = 0x7fffffff;
#pragma unroll
        for (int q = 0; q < 8; ++q) mn = min(mn, (int)(u32)(v[q] >> 32));
        if (__all(mn >= s)) break;
      }
#pragma unroll
      for (int b = 0; b < NB; ++b) {
        hlds[b * NLH + u0] = bitsf((u32)v[2 * b]);
        hlds[b * NLH + u1] = bitsf((u32)v[2 * b + 1]);
      }
    }
    // wave-local: hlds segment written and read only by wave w

    float a0 = 0.f, a1 = 0.f, a2 = 0.f, a3 = 0.f;
    const float* h0 = &hlds[0 * NLH + p * 64];
    const float* h1p = &hlds[1 * NLH + p * 64];
    const float* h2p = &hlds[2 * NLH + p * 64];
    const float* h3p = &hlds[3 * NLH + p * 64];
#pragma unroll
    for (int j = 0; j < 16; ++j) {
      float w0 = wreg[4 * j], w1 = wreg[4 * j + 1], w2 = wreg[4 * j + 2], w3 = wreg[4 * j + 3];
      float4 v0 = *(const float4*)(h0 + 4 * j);
      float4 v1 = *(const float4*)(h1p + 4 * j);
      float4 v2 = *(const float4*)(h2p + 4 * j);
      float4 v3 = *(const float4*)(h3p + 4 * j);
      a0 = fmaf(v0.w, w3, fmaf(v0.z, w2, fmaf(v0.y, w1, fmaf(v0.x, w0, a0))));
      a1 = fmaf(v1.w, w3, fmaf(v1.z, w2, fmaf(v1.y, w1, fmaf(v1.x, w0, a1))));
      a2 = fmaf(v2.w, w3, fmaf(v2.z, w2, fmaf(v2.y, w1, fmaf(v2.x, w0, a2))));
      a3 = fmaf(v3.w, w3, fmaf(v3.z, w2, fmaf(v3.y, w1, fmaf(v3.x, w0, a3))));
    }
    float (*pt)[32][4] = part[s & 1];
    pt[p][r32][0] = a0; pt[p][r32][1] = a1;
    pt[p][r32][2] = a2; pt[p][r32][3] = a3;
    __syncthreads();                                  // single barrier
    if (tid < 32) {
      int u = tid & 7, b = tid >> 3;
      float gsum[4];
#pragma unroll
      for (int G = 0; G < 4; ++G) {
        float t = myxw[G];
#pragma unroll
        for (int pp = 0; pp < 8; ++pp) t += pt[pp][G * 8 + u][b];
        gsum[G] = t;
      }
      float si = 1.f / (1.f + expf(-gsum[0]));
      float sf = 1.f / (1.f + expf(-gsum[1]));
      float so = 1.f / (1.f + expf(-gsum[3]));
      float cn = fmaf(sf, clds[u][b], si * tanhf(gsum[2]));
      float hn = so * tanhf(cn);
      clds[u][b] = cn;
      u64 pk = ((u64)(u32)(s + 1) << 32) | (u64)fbits(hn);
      __hip_atomic_store(&pairs[(size_t)((s + 1) & 1) * (NB * NLH) + b * NLH + blk * 8 + u],
                         pk, __ATOMIC_RELAXED, __HIP_MEMORY_SCOPE_AGENT);
    }
  }

  // FC on block 0
  if (blk == 0) {
    {
      u64* pb = pairs + (size_t)(NT & 1) * (NB * NLH);
      const int u0 = w * 128 + lane, u1 = u0 + 64;
      u64 v[8];
      while (true) {
#pragma unroll
        for (int b = 0; b < NB; ++b) {
          v[2 * b]     = __hip_atomic_load(&pb[b * NLH + u0],
                                           __ATOMIC_RELAXED, __HIP_MEMORY_SCOPE_AGENT);
          v[2 * b + 1] = __hip_atomic_load(&pb[b * NLH + u1],
                                           __ATOMIC_RELAXED, __HIP_MEMORY_SCOPE_AGENT);
        }
        int mn = 0x7fffffff;
#pragma unroll
        for (int q = 0; q < 8; ++q) mn = min(mn, (int)(u32)(v[q] >> 32));
        if (__all(mn >= NT)) break;
      }
#pragma unroll
      for (int b = 0; b < NB; ++b) {
        hlds[b * NLH + u0] = bitsf((u32)v[2 * b]);
        hlds[b * NLH + u1] = bitsf((u32)v[2 * b + 1]);
      }
    }
    __syncthreads();
    int pr = tid >> 3, l = tid & 7;
    int b = pr >> 3, cc = pr & 7;
    const float* hf = hlds + b * NLH;
    float a = 0.f;
    int base = cc * NLH + l * 64;
    for (int j = 0; j < 64; ++j) a = fmaf(hf[l * 64 + j], fcw[base + j], a);
    fcpart[pr][l] = a;
    __syncthreads();
    if (tid < 32) {
      float s = fcb[tid & 7];
#pragma unroll
      for (int l2 = 0; l2 < 8; ++l2) s += fcpart[tid][l2];
      out[tid] = s;
    }
  }
}

// ---------------- host ----------------
extern "C" void kernel_launch(void* const* d_in, const int* in_sizes, int n_in,
                              void* d_out, int out_size, void* d_ws, size_t ws_size,
                              hipStream_t stream)
{
  (void)in_sizes; (void)n_in; (void)out_size; (void)ws_size;
  const float* x    = (const float*)d_in[0];
  const int*   ei   = (const int*)d_in[1];
  const float* Wl1  = (const float*)d_in[2];
  const float* Wr1  = (const float*)d_in[3];
  const float* att1 = (const float*)d_in[4];
  const float* b1   = (const float*)d_in[5];
  const float* Wl2  = (const float*)d_in[6];
  const float* Wr2  = (const float*)d_in[7];
  const float* att2 = (const float*)d_in[8];
  const float* b2   = (const float*)d_in[9];
  const float* Wih  = (const float*)d_in[10];
  const float* Whh  = (const float*)d_in[11];
  const float* bih  = (const float*)d_in[12];
  const float* bhh  = (const float*)d_in[13];
  const float* fcw  = (const float*)d_in[14];
  const float* fcb  = (const float*)d_in[15];

  // workspace layout (~27.6 MB)
  char* ws = (char*)d_ws;
  int* csr_off = (int*)(ws + 0);                    // 49 ints
  int* csr_eid = (int*)(ws + 256);                  // 192 ints -> ends 1024
  u64* pairs   = (u64*)(ws + 1024);                 // 32KB -> 33792
  u16* WTc     = (u16*)(ws + 40960);                // 256KB -> 303104
  u16* WihB    = (u16*)(ws + 303104);               // 12.6MB -> 12886016
  u16* h2b     = (u16*)(ws + 12886016);             // 6MB -> 19177472
  float* xwb   = (float*)(ws + 19177472);           // 8MB -> 27566080
  float* outp  = (float*)d_out;

  setup_kernel<<<1, 64, 0, stream>>>(ei, csr_off, csr_eid);
  wtc_kernel<<<128, 256, 0, stream>>>(Wl2, Wr2, WTc);
  wihb_kernel<<<3072, 256, 0, stream>>>(Wih, WihB);
  gat_fused_kernel<<<NG, 256, 0, stream>>>(x, ei, csr_off, csr_eid,
                                           Wl1, Wr1, att1, b1,
                                           WTc, att2, b2, h2b);
  xw_mfma_kernel<<<256, 256, 0, stream>>>(h2b, WihB, bih, bhh, xwb);
  lstm_kernel<<<LSTM_NBLK, 256, 0, stream>>>(xwb, Whh, fcw, fcb, pairs, outp);
}